// Round 1
// baseline (5616.080 us; speedup 1.0000x reference)
//
#include <hip/hip_runtime.h>

// ---------------- workspace layout (in floats) ----------------
#define WS_PE 0           // pool outputs p1 (16,32,113,113)=6,537,728 / p3
#define WS_PO 6600000     // pool outputs p2 (16,64,55,55)=3,097,600 / p4
#define WS_C  9700000     // conv outputs, max 6,422,528 (c1 chunk of 4 batches)
#define WS_T  16200000    // row-pass tmp, max 3,239,936
#define WS_K  19500000    // K matrices, 66,726 floats
#define WS_AP 19600000    // flattened avgpool output (16,9216)
#define WS_H1 19750000    // fc1 out (16,512)
#define WS_H2 19760000    // fc2 out (16,256)
// total ~19.77M floats = ~79.1 MB

// ---------------- pooling matrix generation (double precision) ----------------
__global__ void gen_pool_mat(float* __restrict__ K, float* __restrict__ KT, int M, int N) {
    int id = blockIdx.x * blockDim.x + threadIdx.x;
    if (id >= M * N) return;
    int s = id / N, u = id % N;
    int n = (M - 1) / 2;
    double theta = (double)s / (double)M - (double)u / (double)N;
    double w = 6.283185307179586476925286766559 * theta;
    double acc = 1.0;
    for (int a = 1; a <= n; ++a) acc += 2.0 * cos(w * (double)a);
    float val = (float)(acc / (double)M);
    K[s * N + u]  = val;
    KT[u * M + s] = val;
}

// ---------------- direct 3x3 "same" convolution (flipped kernel) ----------------
// x: (B, Ci, H, H)  f: (Ci, Co, 3, 3, 2) -- only [...,0] used   y: (B, Co, H, H)
template<int CO_T>
__global__ void conv3x3_k(const float* __restrict__ x, const float* __restrict__ f,
                          float* __restrict__ y, int Ci, int Co, int H) {
    int tilesX = (H + 15) >> 4;
    int tx = blockIdx.x % tilesX, ty = blockIdx.x / tilesX;
    int w = (tx << 4) + threadIdx.x;
    int h = (ty << 4) + threadIdx.y;
    int co0 = blockIdx.y * CO_T;
    int b = blockIdx.z;
    if (h >= H || w >= H) return;
    float acc[CO_T];
#pragma unroll
    for (int t = 0; t < CO_T; ++t) acc[t] = 0.f;
    const float* xb = x + (size_t)b * Ci * H * H;
    for (int ci = 0; ci < Ci; ++ci) {
        const float* xc = xb + (size_t)ci * H * H;
        float xv[3][3];
#pragma unroll
        for (int u = 0; u < 3; ++u) {
            int hh = h + 1 - u;
#pragma unroll
            for (int v = 0; v < 3; ++v) {
                int ww = w + 1 - v;
                xv[u][v] = (hh >= 0 && hh < H && ww >= 0 && ww < H) ? xc[hh * H + ww] : 0.f;
            }
        }
        const float* fc = f + ((size_t)ci * Co + co0) * 18;
#pragma unroll
        for (int t = 0; t < CO_T; ++t) {
#pragma unroll
            for (int u = 0; u < 3; ++u)
#pragma unroll
                for (int v = 0; v < 3; ++v)
                    acc[t] += fc[t * 18 + (u * 3 + v) * 2] * xv[u][v];
        }
    }
    float* yb = y + ((size_t)b * Co + co0) * H * H + h * H + w;
#pragma unroll
    for (int t = 0; t < CO_T; ++t) yb[(size_t)t * H * H] = acc[t];
}

// ---------------- spectral pool: row pass  tmp[bc,s,v] = sum_u K[s,u] x[bc,u,v] ----------------
#define ST_R 16
__global__ void pool_row_k(const float* __restrict__ x, const float* __restrict__ K,
                           float* __restrict__ tmp, int M, int N) {
    __shared__ float Ks[ST_R * 224];
    int bc = blockIdx.y;
    int s0 = blockIdx.x * ST_R;
    int ns = min(ST_R, M - s0);
    int tid = threadIdx.x;
    for (int i = tid; i < ns * N; i += blockDim.x)
        Ks[i] = K[(s0 + i / N) * N + (i % N)];
    __syncthreads();
    int v = tid;
    if (v >= N) return;
    const float* xb = x + (size_t)bc * N * N + v;
    float acc[ST_R];
#pragma unroll
    for (int s = 0; s < ST_R; ++s) acc[s] = 0.f;
    for (int u = 0; u < N; ++u) {
        float xv = xb[(size_t)u * N];
#pragma unroll
        for (int s = 0; s < ST_R; ++s) acc[s] += Ks[s * N + u] * xv;
    }
    float* tb = tmp + (size_t)bc * M * N + v;
    for (int s = 0; s < ns; ++s) tb[(size_t)(s0 + s) * N] = acc[s];
}

// ---------------- spectral pool: col pass  out[bc,s,t] = sum_v tmp[bc,s,v] KT[v,t]  (+ReLU) ----
#define ST_C 8
__global__ void pool_col_k(const float* __restrict__ tmp, const float* __restrict__ KT,
                           float* __restrict__ out, int M, int N, int relu) {
    __shared__ float Ts[ST_C * 224];
    int bc = blockIdx.y;
    int s0 = blockIdx.x * ST_C;
    int ns = min(ST_C, M - s0);
    int tid = threadIdx.x;
    const float* tb = tmp + (size_t)bc * M * N;
    for (int i = tid; i < ns * N; i += blockDim.x)
        Ts[i] = tb[(size_t)(s0 + i / N) * N + (i % N)];
    __syncthreads();
    int t = tid;
    if (t >= M) return;
    float acc[ST_C];
#pragma unroll
    for (int s = 0; s < ST_C; ++s) acc[s] = 0.f;
    for (int v = 0; v < N; ++v) {
        float kv = KT[(size_t)v * M + t];
#pragma unroll
        for (int s = 0; s < ST_C; ++s) acc[s] += Ts[s * N + v] * kv;
    }
    float* ob = out + (size_t)bc * M * M + t;
    for (int s = 0; s < ns; ++s) {
        float r = acc[s];
        if (relu) r = fmaxf(r, 0.f);
        ob[(size_t)(s0 + s) * M] = r;
    }
}

// ---------------- batchnorm over (B,H,W) per channel, in-place; h: (16,256,13,13) ----------------
__global__ void bn_k(float* __restrict__ h, const float* __restrict__ gamma,
                     const float* __restrict__ beta) {
    int c = blockIdx.x;
    int tid = threadIdx.x;
    float s = 0.f, s2 = 0.f;
    for (int i = tid; i < 16 * 169; i += 256) {
        int b = i / 169, hw = i % 169;
        float v = h[((size_t)b * 256 + c) * 169 + hw];
        s += v; s2 += v * v;
    }
    __shared__ float red[256], red2[256];
    red[tid] = s; red2[tid] = s2;
    __syncthreads();
    for (int st = 128; st > 0; st >>= 1) {
        if (tid < st) { red[tid] += red[tid + st]; red2[tid] += red2[tid + st]; }
        __syncthreads();
    }
    __shared__ float sc, sh;
    if (tid == 0) {
        float mean = red[0] / (16.f * 169.f);
        float var  = red2[0] / (16.f * 169.f) - mean * mean;
        float inv  = rsqrtf(var + 1e-5f);
        sc = gamma[c] * inv;
        sh = beta[c] - mean * sc;
    }
    __syncthreads();
    for (int i = tid; i < 16 * 169; i += 256) {
        int b = i / 169, hw = i % 169;
        size_t idx = ((size_t)b * 256 + c) * 169 + hw;
        h[idx] = h[idx] * sc + sh;
    }
}

// ---------------- 3x3 stride-2 VALID avg pool -> flattened (16, 9216) ----------------
__global__ void avgpool_k(const float* __restrict__ h, float* __restrict__ ap) {
    int id = blockIdx.x * 256 + threadIdx.x;
    if (id >= 16 * 256 * 36) return;
    int j = id % 6, i = (id / 6) % 6, c = (id / 36) % 256, b = id / (36 * 256);
    const float* hb = h + ((size_t)b * 256 + c) * 169;
    float s = 0.f;
#pragma unroll
    for (int di = 0; di < 3; ++di)
#pragma unroll
        for (int dj = 0; dj < 3; ++dj)
            s += hb[(2 * i + di) * 13 + (2 * j + dj)];
    ap[(size_t)b * 9216 + c * 36 + i * 6 + j] = s * (1.f / 9.f);
}

// ---------------- FC layer: out[b,o] = (relu)(sum_k h[b,k] W[k,o] + bias[o]), B=16 ----------------
template<int BATCH>
__global__ void fc_k(const float* __restrict__ h, const float* __restrict__ W,
                     const float* __restrict__ bias, float* __restrict__ out,
                     int Kdim, int N, int relu) {
    int o = blockIdx.x * blockDim.x + threadIdx.x;
    if (o >= N) return;
    float acc[BATCH];
#pragma unroll
    for (int b = 0; b < BATCH; ++b) acc[b] = 0.f;
    for (int k = 0; k < Kdim; ++k) {
        float w = W[(size_t)k * N + o];
#pragma unroll
        for (int b = 0; b < BATCH; ++b) acc[b] += h[(size_t)b * Kdim + k] * w;
    }
    for (int b = 0; b < BATCH; ++b) {
        float r = acc[b] + bias[o];
        if (relu) r = fmaxf(r, 0.f);
        out[(size_t)b * N + o] = r;
    }
}

// ---------------- FC3 (256->10) + log_softmax ----------------
__global__ void fc3_softmax_k(const float* __restrict__ h, const float* __restrict__ W,
                              const float* __restrict__ bias, float* __restrict__ out) {
    int b = blockIdx.x;
    int o = threadIdx.x;
    __shared__ float l[10];
    if (o < 10) {
        float acc = bias[o];
        for (int k = 0; k < 256; ++k) acc += h[b * 256 + k] * W[k * 10 + o];
        l[o] = acc;
    }
    __syncthreads();
    if (o == 0) {
        float m = l[0];
        for (int i = 1; i < 10; ++i) m = fmaxf(m, l[i]);
        float s = 0.f;
        for (int i = 0; i < 10; ++i) s += expf(l[i] - m);
        float lse = m + logf(s);
        for (int i = 0; i < 10; ++i) out[b * 10 + i] = l[i] - lse;
    }
}

extern "C" void kernel_launch(void* const* d_in, const int* in_sizes, int n_in,
                              void* d_out, int out_size, void* d_ws, size_t ws_size,
                              hipStream_t stream) {
    const float* x     = (const float*)d_in[0];
    const float* f1    = (const float*)d_in[1];
    const float* f2    = (const float*)d_in[2];
    const float* f3    = (const float*)d_in[3];
    const float* f4    = (const float*)d_in[4];
    const float* f5    = (const float*)d_in[5];
    const float* gamma = (const float*)d_in[6];
    const float* beta  = (const float*)d_in[7];
    const float* W1    = (const float*)d_in[8];
    const float* b1    = (const float*)d_in[9];
    const float* W2    = (const float*)d_in[10];
    const float* b2    = (const float*)d_in[11];
    const float* W3    = (const float*)d_in[12];
    const float* b3    = (const float*)d_in[13];
    float* out = (float*)d_out;
    float* ws  = (float*)d_ws;

    float* PE = ws + WS_PE;
    float* PO = ws + WS_PO;
    float* C  = ws + WS_C;
    float* T  = ws + WS_T;
    float* K1  = ws + WS_K;
    float* K1T = K1 + 25312;
    float* K2  = K1 + 50624;
    float* K2T = K1 + 56839;
    float* K3  = K1 + 63054;
    float* K3T = K1 + 64539;
    float* K4  = K1 + 66024;
    float* K4T = K1 + 66375;
    float* AP = ws + WS_AP;
    float* H1 = ws + WS_H1;
    float* H2 = ws + WS_H2;

    // pooling matrices (exact DFT low-pass operators)
    gen_pool_mat<<<(113 * 224 + 255) / 256, 256, 0, stream>>>(K1, K1T, 113, 224);
    gen_pool_mat<<<(55 * 113 + 255) / 256, 256, 0, stream>>>(K2, K2T, 55, 113);
    gen_pool_mat<<<(27 * 55 + 255) / 256, 256, 0, stream>>>(K3, K3T, 27, 55);
    gen_pool_mat<<<(13 * 27 + 255) / 256, 256, 0, stream>>>(K4, K4T, 13, 27);

    dim3 blk2(16, 16);

    // ---- stage 1: conv1 (3->32, H=224) + pool to 113, chunks of 4 batches ----
    for (int ck = 0; ck < 4; ++ck) {
        int b0 = ck * 4;
        const float* xck = x + (size_t)b0 * 3 * 224 * 224;
        conv3x3_k<4><<<dim3(14 * 14, 32 / 4, 4), blk2, 0, stream>>>(xck, f1, C, 3, 32, 224);
        pool_row_k<<<dim3((113 + ST_R - 1) / ST_R, 4 * 32), 256, 0, stream>>>(C, K1, T, 113, 224);
        pool_col_k<<<dim3((113 + ST_C - 1) / ST_C, 4 * 32), 128, 0, stream>>>(
            T, K1T, PE + (size_t)b0 * 32 * 113 * 113, 113, 224, 1);
    }
    // ---- stage 2: conv2 (32->64, H=113) + pool to 55, chunks of 4 batches ----
    for (int ck = 0; ck < 4; ++ck) {
        int b0 = ck * 4;
        const float* pck = PE + (size_t)b0 * 32 * 113 * 113;
        conv3x3_k<4><<<dim3(8 * 8, 64 / 4, 4), blk2, 0, stream>>>(pck, f2, C, 32, 64, 113);
        pool_row_k<<<dim3((55 + ST_R - 1) / ST_R, 4 * 64), 256, 0, stream>>>(C, K2, T, 55, 113);
        pool_col_k<<<dim3((55 + ST_C - 1) / ST_C, 4 * 64), 128, 0, stream>>>(
            T, K2T, PO + (size_t)b0 * 64 * 55 * 55, 55, 113, 1);
    }
    // ---- stage 3: conv3 (64->128, H=55) + pool to 27, full batch ----
    conv3x3_k<4><<<dim3(4 * 4, 128 / 4, 16), blk2, 0, stream>>>(PO, f3, C, 64, 128, 55);
    pool_row_k<<<dim3((27 + ST_R - 1) / ST_R, 16 * 128), 256, 0, stream>>>(C, K3, T, 27, 55);
    pool_col_k<<<dim3((27 + ST_C - 1) / ST_C, 16 * 128), 128, 0, stream>>>(T, K3T, PE, 27, 55, 1);

    // ---- stage 4: conv4 (128->256, H=27) + pool to 13, full batch ----
    conv3x3_k<4><<<dim3(2 * 2, 256 / 4, 16), blk2, 0, stream>>>(PE, f4, C, 128, 256, 27);
    pool_row_k<<<dim3((13 + ST_R - 1) / ST_R, 16 * 256), 256, 0, stream>>>(C, K4, T, 13, 27);
    pool_col_k<<<dim3((13 + ST_C - 1) / ST_C, 16 * 256), 128, 0, stream>>>(T, K4T, PO, 13, 27, 1);

    // ---- conv5 (256->256, H=13), no pool ----
    conv3x3_k<4><<<dim3(1, 256 / 4, 16), blk2, 0, stream>>>(PO, f5, C, 256, 256, 13);

    // ---- batchnorm (in place) ----
    bn_k<<<256, 256, 0, stream>>>(C, gamma, beta);

    // ---- avg pool 3x3 stride 2 -> flattened (16, 9216) ----
    avgpool_k<<<(16 * 256 * 36 + 255) / 256, 256, 0, stream>>>(C, AP);

    // ---- FC head ----
    fc_k<16><<<2, 256, 0, stream>>>(AP, W1, b1, H1, 9216, 512, 1);
    fc_k<16><<<1, 256, 0, stream>>>(H1, W2, b2, H2, 512, 256, 1);
    fc3_softmax_k<<<16, 64, 0, stream>>>(H2, W3, b3, out);
}

// Round 2
// 3071.100 us; speedup vs baseline: 1.8287x; 1.8287x over previous
//
#include <hip/hip_runtime.h>

// ---------------- workspace layout (in floats) ----------------
#define WS_PE 0           // pool outputs p1 (16,32,113,113)=6,537,728 / p3
#define WS_PO 6600000     // pool outputs p2 (16,64,55,55)=3,097,600 / p4
#define WS_C  9700000     // conv outputs, max 6,422,528 (c1 chunk of 4 batches)
#define WS_T  16200000    // row-pass tmp, max 3,239,936; reused as FC split-K partials
#define WS_K  19500000    // K matrices, 66,726 floats
#define WS_AP 19600000    // flattened avgpool output (16,9216)
#define WS_H1 19750000    // fc1 out (16,512)
#define WS_H2 19760000    // fc2 out (16,256)
// total ~19.77M floats = ~79.1 MB

// ---------------- pooling matrix generation (double precision) ----------------
__global__ void gen_pool_mat(float* __restrict__ K, float* __restrict__ KT, int M, int N) {
    int id = blockIdx.x * blockDim.x + threadIdx.x;
    if (id >= M * N) return;
    int s = id / N, u = id % N;
    int n = (M - 1) / 2;
    double theta = (double)s / (double)M - (double)u / (double)N;
    double w = 6.283185307179586476925286766559 * theta;
    double acc = 1.0;
    for (int a = 1; a <= n; ++a) acc += 2.0 * cos(w * (double)a);
    float val = (float)(acc / (double)M);
    K[s * N + u]  = val;
    KT[u * M + s] = val;
}

// ---------------- direct 3x3 "same" convolution (flipped kernel) ----------------
// x: (B, Ci, H, H)  f: (Ci, Co, 3, 3, 2) -- only [...,0] used   y: (B, Co, H, H)
template<int CO_T>
__global__ void conv3x3_k(const float* __restrict__ x, const float* __restrict__ f,
                          float* __restrict__ y, int Ci, int Co, int H) {
    int tilesX = (H + 15) >> 4;
    int tx = blockIdx.x % tilesX, ty = blockIdx.x / tilesX;
    int w = (tx << 4) + threadIdx.x;
    int h = (ty << 4) + threadIdx.y;
    int co0 = blockIdx.y * CO_T;
    int b = blockIdx.z;
    if (h >= H || w >= H) return;
    float acc[CO_T];
#pragma unroll
    for (int t = 0; t < CO_T; ++t) acc[t] = 0.f;
    const float* xb = x + (size_t)b * Ci * H * H;
    for (int ci = 0; ci < Ci; ++ci) {
        const float* xc = xb + (size_t)ci * H * H;
        float xv[3][3];
#pragma unroll
        for (int u = 0; u < 3; ++u) {
            int hh = h + 1 - u;
#pragma unroll
            for (int v = 0; v < 3; ++v) {
                int ww = w + 1 - v;
                xv[u][v] = (hh >= 0 && hh < H && ww >= 0 && ww < H) ? xc[hh * H + ww] : 0.f;
            }
        }
        const float* fc = f + ((size_t)ci * Co + co0) * 18;
#pragma unroll
        for (int t = 0; t < CO_T; ++t) {
#pragma unroll
            for (int u = 0; u < 3; ++u)
#pragma unroll
                for (int v = 0; v < 3; ++v)
                    acc[t] += fc[t * 18 + (u * 3 + v) * 2] * xv[u][v];
        }
    }
    float* yb = y + ((size_t)b * Co + co0) * H * H + h * H + w;
#pragma unroll
    for (int t = 0; t < CO_T; ++t) yb[(size_t)t * H * H] = acc[t];
}

// ---------------- spectral pool: row pass  tmp[bc,s,v] = sum_u K[s,u] x[bc,u,v] ----------------
#define ST_R 16
__global__ void pool_row_k(const float* __restrict__ x, const float* __restrict__ K,
                           float* __restrict__ tmp, int M, int N) {
    __shared__ float Ks[ST_R * 224];
    int bc = blockIdx.y;
    int s0 = blockIdx.x * ST_R;
    int ns = min(ST_R, M - s0);
    int tid = threadIdx.x;
    for (int i = tid; i < ns * N; i += blockDim.x)
        Ks[i] = K[(s0 + i / N) * N + (i % N)];
    __syncthreads();
    int v = tid;
    if (v >= N) return;
    const float* xb = x + (size_t)bc * N * N + v;
    float acc[ST_R];
#pragma unroll
    for (int s = 0; s < ST_R; ++s) acc[s] = 0.f;
    for (int u = 0; u < N; ++u) {
        float xv = xb[(size_t)u * N];
#pragma unroll
        for (int s = 0; s < ST_R; ++s) acc[s] += Ks[s * N + u] * xv;
    }
    float* tb = tmp + (size_t)bc * M * N + v;
    for (int s = 0; s < ns; ++s) tb[(size_t)(s0 + s) * N] = acc[s];
}

// ---------------- spectral pool: col pass  out[bc,s,t] = sum_v tmp[bc,s,v] KT[v,t]  (+ReLU) ----
#define ST_C 8
__global__ void pool_col_k(const float* __restrict__ tmp, const float* __restrict__ KT,
                           float* __restrict__ out, int M, int N, int relu) {
    __shared__ float Ts[ST_C * 224];
    int bc = blockIdx.y;
    int s0 = blockIdx.x * ST_C;
    int ns = min(ST_C, M - s0);
    int tid = threadIdx.x;
    const float* tb = tmp + (size_t)bc * M * N;
    for (int i = tid; i < ns * N; i += blockDim.x)
        Ts[i] = tb[(size_t)(s0 + i / N) * N + (i % N)];
    __syncthreads();
    int t = tid;
    if (t >= M) return;
    float acc[ST_C];
#pragma unroll
    for (int s = 0; s < ST_C; ++s) acc[s] = 0.f;
    for (int v = 0; v < N; ++v) {
        float kv = KT[(size_t)v * M + t];
#pragma unroll
        for (int s = 0; s < ST_C; ++s) acc[s] += Ts[s * N + v] * kv;
    }
    float* ob = out + (size_t)bc * M * M + t;
    for (int s = 0; s < ns; ++s) {
        float r = acc[s];
        if (relu) r = fmaxf(r, 0.f);
        ob[(size_t)(s0 + s) * M] = r;
    }
}

// ---------------- batchnorm over (B,H,W) per channel, in-place; h: (16,256,13,13) ----------------
__global__ void bn_k(float* __restrict__ h, const float* __restrict__ gamma,
                     const float* __restrict__ beta) {
    int c = blockIdx.x;
    int tid = threadIdx.x;
    float s = 0.f, s2 = 0.f;
    for (int i = tid; i < 16 * 169; i += 256) {
        int b = i / 169, hw = i % 169;
        float v = h[((size_t)b * 256 + c) * 169 + hw];
        s += v; s2 += v * v;
    }
    __shared__ float red[256], red2[256];
    red[tid] = s; red2[tid] = s2;
    __syncthreads();
    for (int st = 128; st > 0; st >>= 1) {
        if (tid < st) { red[tid] += red[tid + st]; red2[tid] += red2[tid + st]; }
        __syncthreads();
    }
    __shared__ float sc, sh;
    if (tid == 0) {
        float mean = red[0] / (16.f * 169.f);
        float var  = red2[0] / (16.f * 169.f) - mean * mean;
        float inv  = rsqrtf(var + 1e-5f);
        sc = gamma[c] * inv;
        sh = beta[c] - mean * sc;
    }
    __syncthreads();
    for (int i = tid; i < 16 * 169; i += 256) {
        int b = i / 169, hw = i % 169;
        size_t idx = ((size_t)b * 256 + c) * 169 + hw;
        h[idx] = h[idx] * sc + sh;
    }
}

// ---------------- 3x3 stride-2 VALID avg pool -> flattened (16, 9216) ----------------
__global__ void avgpool_k(const float* __restrict__ h, float* __restrict__ ap) {
    int id = blockIdx.x * 256 + threadIdx.x;
    if (id >= 16 * 256 * 36) return;
    int j = id % 6, i = (id / 6) % 6, c = (id / 36) % 256, b = id / (36 * 256);
    const float* hb = h + ((size_t)b * 256 + c) * 169;
    float s = 0.f;
#pragma unroll
    for (int di = 0; di < 3; ++di)
#pragma unroll
        for (int dj = 0; dj < 3; ++dj)
            s += hb[(2 * i + di) * 13 + (2 * j + dj)];
    ap[(size_t)b * 9216 + c * 36 + i * 6 + j] = s * (1.f / 9.f);
}

// ---------------- split-K FC partial kernel ----------------
// grid (N/64, KS), block (64, 4). Each block: o-range [bx*64, bx*64+64),
// k-range [by*KLEN, (by+1)*KLEN). Partials P[by][b][o] (BATCH=16).
template<int BATCH, int KLEN>
__global__ void fc_part_k(const float* __restrict__ h, const float* __restrict__ W,
                          float* __restrict__ P, int Kdim, int N) {
    __shared__ float hs[BATCH * KLEN];
    __shared__ float red[BATCH * 64];
    int tx = threadIdx.x, ty = threadIdx.y;
    int tid = ty * 64 + tx;
    int o = blockIdx.x * 64 + tx;
    int k0 = blockIdx.y * KLEN;
    // stage h chunk into LDS: hs[b][k]
    for (int i = tid; i < BATCH * KLEN; i += 256) {
        int b = i / KLEN, k = i % KLEN;
        hs[i] = h[(size_t)b * Kdim + k0 + k];
    }
    __syncthreads();
    float acc[BATCH];
#pragma unroll
    for (int b = 0; b < BATCH; ++b) acc[b] = 0.f;
    for (int k = ty; k < KLEN; k += 4) {
        float w = W[(size_t)(k0 + k) * N + o];
#pragma unroll
        for (int b = 0; b < BATCH; ++b) acc[b] += hs[b * KLEN + k] * w;
    }
    // reduce across ty (4) via LDS
    for (int kz = 0; kz < 4; ++kz) {
        if (ty == kz) {
#pragma unroll
            for (int b = 0; b < BATCH; ++b) {
                if (kz == 0) red[b * 64 + tx] = acc[b];
                else         red[b * 64 + tx] += acc[b];
            }
        }
        __syncthreads();
    }
    if (ty == 0) {
#pragma unroll
        for (int b = 0; b < BATCH; ++b)
            P[((size_t)blockIdx.y * BATCH + b) * N + o] = red[b * 64 + tx];
    }
}

// ---------------- FC reduce: out[b,o] = (relu)(sum_ks P[ks][b][o] + bias[o]) ----------------
template<int BATCH>
__global__ void fc_reduce_k(const float* __restrict__ P, const float* __restrict__ bias,
                            float* __restrict__ out, int N, int KS, int relu) {
    int id = blockIdx.x * 256 + threadIdx.x;
    if (id >= BATCH * N) return;
    int b = id / N, o = id % N;
    float s = bias[o];
    for (int ks = 0; ks < KS; ++ks) s += P[((size_t)ks * BATCH + b) * N + o];
    if (relu) s = fmaxf(s, 0.f);
    out[(size_t)b * N + o] = s;
}

// ---------------- FC3 (256->10) + log_softmax ----------------
__global__ void fc3_softmax_k(const float* __restrict__ h, const float* __restrict__ W,
                              const float* __restrict__ bias, float* __restrict__ out) {
    int b = blockIdx.x;
    int o = threadIdx.x;
    __shared__ float l[10];
    if (o < 10) {
        float acc = bias[o];
        for (int k = 0; k < 256; ++k) acc += h[b * 256 + k] * W[k * 10 + o];
        l[o] = acc;
    }
    __syncthreads();
    if (o == 0) {
        float m = l[0];
        for (int i = 1; i < 10; ++i) m = fmaxf(m, l[i]);
        float s = 0.f;
        for (int i = 0; i < 10; ++i) s += expf(l[i] - m);
        float lse = m + logf(s);
        for (int i = 0; i < 10; ++i) out[b * 10 + i] = l[i] - lse;
    }
}

extern "C" void kernel_launch(void* const* d_in, const int* in_sizes, int n_in,
                              void* d_out, int out_size, void* d_ws, size_t ws_size,
                              hipStream_t stream) {
    const float* x     = (const float*)d_in[0];
    const float* f1    = (const float*)d_in[1];
    const float* f2    = (const float*)d_in[2];
    const float* f3    = (const float*)d_in[3];
    const float* f4    = (const float*)d_in[4];
    const float* f5    = (const float*)d_in[5];
    const float* gamma = (const float*)d_in[6];
    const float* beta  = (const float*)d_in[7];
    const float* W1    = (const float*)d_in[8];
    const float* b1    = (const float*)d_in[9];
    const float* W2    = (const float*)d_in[10];
    const float* b2    = (const float*)d_in[11];
    const float* W3    = (const float*)d_in[12];
    const float* b3    = (const float*)d_in[13];
    float* out = (float*)d_out;
    float* ws  = (float*)d_ws;

    float* PE = ws + WS_PE;
    float* PO = ws + WS_PO;
    float* C  = ws + WS_C;
    float* T  = ws + WS_T;
    float* K1  = ws + WS_K;
    float* K1T = K1 + 25312;
    float* K2  = K1 + 50624;
    float* K2T = K1 + 56839;
    float* K3  = K1 + 63054;
    float* K3T = K1 + 64539;
    float* K4  = K1 + 66024;
    float* K4T = K1 + 66375;
    float* AP = ws + WS_AP;
    float* H1 = ws + WS_H1;
    float* H2 = ws + WS_H2;
    float* P  = ws + WS_T;   // FC split-K partials (T is free by FC time)

    // pooling matrices (exact DFT low-pass operators)
    gen_pool_mat<<<(113 * 224 + 255) / 256, 256, 0, stream>>>(K1, K1T, 113, 224);
    gen_pool_mat<<<(55 * 113 + 255) / 256, 256, 0, stream>>>(K2, K2T, 55, 113);
    gen_pool_mat<<<(27 * 55 + 255) / 256, 256, 0, stream>>>(K3, K3T, 27, 55);
    gen_pool_mat<<<(13 * 27 + 255) / 256, 256, 0, stream>>>(K4, K4T, 13, 27);

    dim3 blk2(16, 16);

    // ---- stage 1: conv1 (3->32, H=224) + pool to 113, chunks of 4 batches ----
    for (int ck = 0; ck < 4; ++ck) {
        int b0 = ck * 4;
        const float* xck = x + (size_t)b0 * 3 * 224 * 224;
        conv3x3_k<4><<<dim3(14 * 14, 32 / 4, 4), blk2, 0, stream>>>(xck, f1, C, 3, 32, 224);
        pool_row_k<<<dim3((113 + ST_R - 1) / ST_R, 4 * 32), 256, 0, stream>>>(C, K1, T, 113, 224);
        pool_col_k<<<dim3((113 + ST_C - 1) / ST_C, 4 * 32), 128, 0, stream>>>(
            T, K1T, PE + (size_t)b0 * 32 * 113 * 113, 113, 224, 1);
    }
    // ---- stage 2: conv2 (32->64, H=113) + pool to 55, chunks of 4 batches ----
    for (int ck = 0; ck < 4; ++ck) {
        int b0 = ck * 4;
        const float* pck = PE + (size_t)b0 * 32 * 113 * 113;
        conv3x3_k<4><<<dim3(8 * 8, 64 / 4, 4), blk2, 0, stream>>>(pck, f2, C, 32, 64, 113);
        pool_row_k<<<dim3((55 + ST_R - 1) / ST_R, 4 * 64), 256, 0, stream>>>(C, K2, T, 55, 113);
        pool_col_k<<<dim3((55 + ST_C - 1) / ST_C, 4 * 64), 128, 0, stream>>>(
            T, K2T, PO + (size_t)b0 * 64 * 55 * 55, 55, 113, 1);
    }
    // ---- stage 3: conv3 (64->128, H=55) + pool to 27, full batch ----
    conv3x3_k<4><<<dim3(4 * 4, 128 / 4, 16), blk2, 0, stream>>>(PO, f3, C, 64, 128, 55);
    pool_row_k<<<dim3((27 + ST_R - 1) / ST_R, 16 * 128), 256, 0, stream>>>(C, K3, T, 27, 55);
    pool_col_k<<<dim3((27 + ST_C - 1) / ST_C, 16 * 128), 128, 0, stream>>>(T, K3T, PE, 27, 55, 1);

    // ---- stage 4: conv4 (128->256, H=27) + pool to 13, full batch ----
    conv3x3_k<4><<<dim3(2 * 2, 256 / 4, 16), blk2, 0, stream>>>(PE, f4, C, 128, 256, 27);
    pool_row_k<<<dim3((13 + ST_R - 1) / ST_R, 16 * 256), 256, 0, stream>>>(C, K4, T, 13, 27);
    pool_col_k<<<dim3((13 + ST_C - 1) / ST_C, 16 * 256), 128, 0, stream>>>(T, K4T, PO, 13, 27, 1);

    // ---- conv5 (256->256, H=13), no pool ----
    conv3x3_k<4><<<dim3(1, 256 / 4, 16), blk2, 0, stream>>>(PO, f5, C, 256, 256, 13);

    // ---- batchnorm (in place) ----
    bn_k<<<256, 256, 0, stream>>>(C, gamma, beta);

    // ---- avg pool 3x3 stride 2 -> flattened (16, 9216) ----
    avgpool_k<<<(16 * 256 * 36 + 255) / 256, 256, 0, stream>>>(C, AP);

    // ---- FC head: split-K (36 and 8 k-blocks), then reduce+bias+relu ----
    fc_part_k<16, 256><<<dim3(512 / 64, 36), dim3(64, 4), 0, stream>>>(AP, W1, P, 9216, 512);
    fc_reduce_k<16><<<(16 * 512 + 255) / 256, 256, 0, stream>>>(P, b1, H1, 512, 36, 1);
    fc_part_k<16, 64><<<dim3(256 / 64, 8), dim3(64, 4), 0, stream>>>(H1, W2, P, 512, 256);
    fc_reduce_k<16><<<(16 * 256 + 255) / 256, 256, 0, stream>>>(P, b2, H2, 256, 8, 1);
    fc3_softmax_k<<<16, 64, 0, stream>>>(H2, W3, b3, out);
}

// Round 3
// 1116.444 us; speedup vs baseline: 5.0303x; 2.7508x over previous
//
#include <hip/hip_runtime.h>
#include <hip/hip_bf16.h>

typedef __attribute__((ext_vector_type(8))) short short8_t;
typedef __attribute__((ext_vector_type(4))) float float4_t;

// ---------------- workspace layout (in floats) ----------------
#define WS_PE 0           // pool outputs p1 (16,32,113,113)=6,537,728 / p3
#define WS_PO 6600000     // pool outputs p2 (16,64,55,55)=3,097,600 / p4
#define WS_C  9700000     // conv outputs, max 6,422,528 (c1 chunk of 4 batches)
#define WS_T  16200000    // row-pass tmp, max 3,239,936; reused as FC split-K partials
#define WS_K  19500000    // K matrices, 66,726 floats
#define WS_AP 19600000    // flattened avgpool output (16,9216)
#define WS_H1 19750000    // fc1 out (16,512)
#define WS_H2 19760000    // fc2 out (16,256)
#define WS_PK 19770000    // packed bf16 filters, 977,920 ushort = 488,960 floats
// total ~20.26M floats = ~81.0 MB

#define CPAD 40  // ci stride in bf16 elems (80B -> good bank spread for ds_read_b128)

static __device__ __forceinline__ unsigned short f2bf(float v) {
    __hip_bfloat16 h = __float2bfloat16(v);
    return *(unsigned short*)&h;
}

// ---------------- pooling matrix generation (double precision) ----------------
__global__ void gen_pool_mat(float* __restrict__ K, float* __restrict__ KT, int M, int N) {
    int id = blockIdx.x * blockDim.x + threadIdx.x;
    if (id >= M * N) return;
    int s = id / N, u = id % N;
    int n = (M - 1) / 2;
    double theta = (double)s / (double)M - (double)u / (double)N;
    double w = 6.283185307179586476925286766559 * theta;
    double acc = 1.0;
    for (int a = 1; a <= n; ++a) acc += 2.0 * cos(w * (double)a);
    float val = (float)(acc / (double)M);
    K[s * N + u]  = val;
    KT[u * M + s] = val;
}

// ---------------- filter pack: f(Ci,Co,3,3,2) -> A frags [Co/16][Ci/32][9][64][8] bf16 ----
__global__ void pack_f_k(const float* __restrict__ f, unsigned short* __restrict__ A,
                         int Ci, int Co) {
    int id = blockIdx.x * 256 + threadIdx.x;
    int nci = Ci >> 5;
    int total = (Co >> 4) * nci * 9 * 512;
    if (id >= total) return;
    int j = id & 7, lane = (id >> 3) & 63;
    int uv = (id >> 9) % 9;
    int rest = id / (512 * 9);
    int cc = rest % nci, co_blk = rest / nci;
    int m = lane & 15, k = ((lane >> 4) << 3) + j;
    int ci = (cc << 5) + k, co = (co_blk << 4) + m;
    A[id] = f2bf(f[((size_t)(ci * Co + co) * 9 + uv) * 2]);
}

// ---- conv1 pack: k = ci*9+uv (27, zero-padded to 32), layout [2][64][8] ----
__global__ void pack_f1_k(const float* __restrict__ f, unsigned short* __restrict__ A) {
    int id = blockIdx.x * 256 + threadIdx.x;
    if (id >= 2 * 512) return;
    int j = id & 7, lane = (id >> 3) & 63, co_blk = id >> 9;
    int m = lane & 15, k = ((lane >> 4) << 3) + j;
    float v = 0.f;
    if (k < 27) {
        int ci = k / 9, uv = k % 9;
        v = f[((size_t)(ci * 32 + co_blk * 16 + m) * 9 + uv) * 2];
    }
    A[id] = f2bf(v);
}

// ---------------- MFMA conv (Ci mult of 32, Co mult of 32): 9 shifted GEMMs ----------------
// grid (q_tiles, Co/32, B*H), block 256. Wave w: co_sub=w>>1, n_sub=w&1.
__global__ void conv_mfma_k(const float* __restrict__ x, const unsigned short* __restrict__ Apk,
                            float* __restrict__ y, int Ci, int Co, int H) {
    __shared__ unsigned short xs[3 * 34 * CPAD];
    int p = blockIdx.z % H, b = blockIdx.z / H;
    int q0 = blockIdx.x << 5;
    int co0 = blockIdx.y << 5;
    int tid = threadIdx.x;
    int lane = tid & 63, w = tid >> 6;
    int co_sub = w >> 1, n_sub = w & 1;
    int n_off = n_sub << 4;
    int nci = Ci >> 5;
    int kb = ((lane >> 4) << 3);
    float4_t acc = {0.f, 0.f, 0.f, 0.f};
    const float* xb = x + (size_t)b * Ci * H * H;
    int co_blk = (co0 >> 4) + co_sub;
    for (int cc = 0; cc < nci; ++cc) {
        for (int e = tid; e < 32 * 3 * 34; e += 256) {
            int ci = e / 102, rc = e % 102, r = rc / 34, c = rc % 34;
            int gp = p - 1 + r, gq = q0 - 1 + c;
            float v = 0.f;
            if ((unsigned)gp < (unsigned)H && (unsigned)gq < (unsigned)H)
                v = xb[((size_t)((cc << 5) + ci) * H + gp) * H + gq];
            xs[(r * 34 + c) * CPAD + ci] = f2bf(v);
        }
        __syncthreads();
        const unsigned short* Ap = Apk + (((size_t)co_blk * nci + cc) * 9) * 512;
#pragma unroll
        for (int uv = 0; uv < 9; ++uv) {
            int u = uv / 3, v = uv % 3;
            short8_t af = *(const short8_t*)(Ap + ((uv * 64 + lane) << 3));
            int r = 2 - u;
            int c = n_off + (lane & 15) + 2 - v;
            short8_t bf = *(const short8_t*)(&xs[(r * 34 + c) * CPAD + kb]);
            acc = __builtin_amdgcn_mfma_f32_16x16x32_bf16(af, bf, acc, 0, 0, 0);
        }
        __syncthreads();
    }
    int n = lane & 15, mg = (lane >> 4) << 2;
    int q = q0 + n_off + n;
    if (q < H) {
        float* yb = y + (((size_t)b * Co + co0 + (co_sub << 4)) * H + p) * H + q;
#pragma unroll
        for (int r2 = 0; r2 < 4; ++r2)
            yb[(size_t)(mg + r2) * H * H] = acc[r2];
    }
}

// ---------------- MFMA conv1 (Ci=3, Co=32): im2col K=27 padded to 32 ----------------
// grid (q_tiles, 1, B*H), block 256.
__global__ void conv1_mfma_k(const float* __restrict__ x, const unsigned short* __restrict__ Apk,
                             float* __restrict__ y, int H) {
    __shared__ unsigned short xs[32 * CPAD];
    int p = blockIdx.z % H, b = blockIdx.z / H;
    int q0 = blockIdx.x << 5;
    int tid = threadIdx.x;
    int lane = tid & 63, w = tid >> 6;
    int co_sub = w >> 1, n_sub = w & 1;
    int n_off = n_sub << 4;
    int kb = ((lane >> 4) << 3);
    const float* xb = x + (size_t)b * 3 * H * H;
    for (int e = tid; e < 1024; e += 256) {
        int n = e >> 5, k = e & 31;
        float val = 0.f;
        if (k < 27) {
            int ci = k / 9, uv = k % 9, u = uv / 3, v = uv % 3;
            int gp = p + 1 - u, gq = q0 + n + 1 - v;
            if ((unsigned)gp < (unsigned)H && (unsigned)gq < (unsigned)H)
                val = xb[((size_t)ci * H + gp) * H + gq];
        }
        xs[n * CPAD + k] = f2bf(val);
    }
    __syncthreads();
    short8_t af = *(const short8_t*)(Apk + ((co_sub * 64 + lane) << 3));
    short8_t bf = *(const short8_t*)(&xs[(n_off + (lane & 15)) * CPAD + kb]);
    float4_t acc = {0.f, 0.f, 0.f, 0.f};
    acc = __builtin_amdgcn_mfma_f32_16x16x32_bf16(af, bf, acc, 0, 0, 0);
    int n = lane & 15, mg = (lane >> 4) << 2;
    int q = q0 + n_off + n;
    if (q < H) {
        float* yb = y + (((size_t)b * 32 + (co_sub << 4)) * H + p) * H + q;
#pragma unroll
        for (int r2 = 0; r2 < 4; ++r2)
            yb[(size_t)(mg + r2) * H * H] = acc[r2];
    }
}

// ---------------- spectral pool: row pass  tmp[bc,s,v] = sum_u K[s,u] x[bc,u,v] ----------------
#define ST_R 16
__global__ void pool_row_k(const float* __restrict__ x, const float* __restrict__ K,
                           float* __restrict__ tmp, int M, int N) {
    __shared__ float Ks[ST_R * 224];
    int bc = blockIdx.y;
    int s0 = blockIdx.x * ST_R;
    int ns = min(ST_R, M - s0);
    int tid = threadIdx.x;
    for (int i = tid; i < ns * N; i += blockDim.x)
        Ks[i] = K[(s0 + i / N) * N + (i % N)];
    __syncthreads();
    int v = tid;
    if (v >= N) return;
    const float* xb = x + (size_t)bc * N * N + v;
    float acc[ST_R];
#pragma unroll
    for (int s = 0; s < ST_R; ++s) acc[s] = 0.f;
    for (int u = 0; u < N; ++u) {
        float xv = xb[(size_t)u * N];
#pragma unroll
        for (int s = 0; s < ST_R; ++s) acc[s] += Ks[s * N + u] * xv;
    }
    float* tb = tmp + (size_t)bc * M * N + v;
    for (int s = 0; s < ns; ++s) tb[(size_t)(s0 + s) * N] = acc[s];
}

// ---------------- spectral pool: col pass  out[bc,s,t] = sum_v tmp[bc,s,v] KT[v,t]  (+ReLU) ----
#define ST_C 8
__global__ void pool_col_k(const float* __restrict__ tmp, const float* __restrict__ KT,
                           float* __restrict__ out, int M, int N, int relu) {
    __shared__ float Ts[ST_C * 224];
    int bc = blockIdx.y;
    int s0 = blockIdx.x * ST_C;
    int ns = min(ST_C, M - s0);
    int tid = threadIdx.x;
    const float* tb = tmp + (size_t)bc * M * N;
    for (int i = tid; i < ns * N; i += blockDim.x)
        Ts[i] = tb[(size_t)(s0 + i / N) * N + (i % N)];
    __syncthreads();
    int t = tid;
    if (t >= M) return;
    float acc[ST_C];
#pragma unroll
    for (int s = 0; s < ST_C; ++s) acc[s] = 0.f;
    for (int v = 0; v < N; ++v) {
        float kv = KT[(size_t)v * M + t];
#pragma unroll
        for (int s = 0; s < ST_C; ++s) acc[s] += Ts[s * N + v] * kv;
    }
    float* ob = out + (size_t)bc * M * M + t;
    for (int s = 0; s < ns; ++s) {
        float r = acc[s];
        if (relu) r = fmaxf(r, 0.f);
        ob[(size_t)(s0 + s) * M] = r;
    }
}

// ---------------- batchnorm over (B,H,W) per channel, in-place; h: (16,256,13,13) ----------------
__global__ void bn_k(float* __restrict__ h, const float* __restrict__ gamma,
                     const float* __restrict__ beta) {
    int c = blockIdx.x;
    int tid = threadIdx.x;
    float s = 0.f, s2 = 0.f;
    for (int i = tid; i < 16 * 169; i += 256) {
        int b = i / 169, hw = i % 169;
        float v = h[((size_t)b * 256 + c) * 169 + hw];
        s += v; s2 += v * v;
    }
    __shared__ float red[256], red2[256];
    red[tid] = s; red2[tid] = s2;
    __syncthreads();
    for (int st = 128; st > 0; st >>= 1) {
        if (tid < st) { red[tid] += red[tid + st]; red2[tid] += red2[tid + st]; }
        __syncthreads();
    }
    __shared__ float sc, sh;
    if (tid == 0) {
        float mean = red[0] / (16.f * 169.f);
        float var  = red2[0] / (16.f * 169.f) - mean * mean;
        float inv  = rsqrtf(var + 1e-5f);
        sc = gamma[c] * inv;
        sh = beta[c] - mean * sc;
    }
    __syncthreads();
    for (int i = tid; i < 16 * 169; i += 256) {
        int b = i / 169, hw = i % 169;
        size_t idx = ((size_t)b * 256 + c) * 169 + hw;
        h[idx] = h[idx] * sc + sh;
    }
}

// ---------------- 3x3 stride-2 VALID avg pool -> flattened (16, 9216) ----------------
__global__ void avgpool_k(const float* __restrict__ h, float* __restrict__ ap) {
    int id = blockIdx.x * 256 + threadIdx.x;
    if (id >= 16 * 256 * 36) return;
    int j = id % 6, i = (id / 6) % 6, c = (id / 36) % 256, b = id / (36 * 256);
    const float* hb = h + ((size_t)b * 256 + c) * 169;
    float s = 0.f;
#pragma unroll
    for (int di = 0; di < 3; ++di)
#pragma unroll
        for (int dj = 0; dj < 3; ++dj)
            s += hb[(2 * i + di) * 13 + (2 * j + dj)];
    ap[(size_t)b * 9216 + c * 36 + i * 6 + j] = s * (1.f / 9.f);
}

// ---------------- split-K FC partial kernel ----------------
template<int BATCH, int KLEN>
__global__ void fc_part_k(const float* __restrict__ h, const float* __restrict__ W,
                          float* __restrict__ P, int Kdim, int N) {
    __shared__ float hs[BATCH * KLEN];
    __shared__ float red[BATCH * 64];
    int tx = threadIdx.x, ty = threadIdx.y;
    int tid = ty * 64 + tx;
    int o = blockIdx.x * 64 + tx;
    int k0 = blockIdx.y * KLEN;
    for (int i = tid; i < BATCH * KLEN; i += 256) {
        int b = i / KLEN, k = i % KLEN;
        hs[i] = h[(size_t)b * Kdim + k0 + k];
    }
    __syncthreads();
    float acc[BATCH];
#pragma unroll
    for (int b = 0; b < BATCH; ++b) acc[b] = 0.f;
    for (int k = ty; k < KLEN; k += 4) {
        float w = W[(size_t)(k0 + k) * N + o];
#pragma unroll
        for (int b = 0; b < BATCH; ++b) acc[b] += hs[b * KLEN + k] * w;
    }
    for (int kz = 0; kz < 4; ++kz) {
        if (ty == kz) {
#pragma unroll
            for (int b = 0; b < BATCH; ++b) {
                if (kz == 0) red[b * 64 + tx] = acc[b];
                else         red[b * 64 + tx] += acc[b];
            }
        }
        __syncthreads();
    }
    if (ty == 0) {
#pragma unroll
        for (int b = 0; b < BATCH; ++b)
            P[((size_t)blockIdx.y * BATCH + b) * N + o] = red[b * 64 + tx];
    }
}

// ---------------- FC reduce: out[b,o] = (relu)(sum_ks P[ks][b][o] + bias[o]) ----------------
template<int BATCH>
__global__ void fc_reduce_k(const float* __restrict__ P, const float* __restrict__ bias,
                            float* __restrict__ out, int N, int KS, int relu) {
    int id = blockIdx.x * 256 + threadIdx.x;
    if (id >= BATCH * N) return;
    int b = id / N, o = id % N;
    float s = bias[o];
    for (int ks = 0; ks < KS; ++ks) s += P[((size_t)ks * BATCH + b) * N + o];
    if (relu) s = fmaxf(s, 0.f);
    out[(size_t)b * N + o] = s;
}

// ---------------- FC3 (256->10) + log_softmax ----------------
__global__ void fc3_softmax_k(const float* __restrict__ h, const float* __restrict__ W,
                              const float* __restrict__ bias, float* __restrict__ out) {
    int b = blockIdx.x;
    int o = threadIdx.x;
    __shared__ float l[10];
    if (o < 10) {
        float acc = bias[o];
        for (int k = 0; k < 256; ++k) acc += h[b * 256 + k] * W[k * 10 + o];
        l[o] = acc;
    }
    __syncthreads();
    if (o == 0) {
        float m = l[0];
        for (int i = 1; i < 10; ++i) m = fmaxf(m, l[i]);
        float s = 0.f;
        for (int i = 0; i < 10; ++i) s += expf(l[i] - m);
        float lse = m + logf(s);
        for (int i = 0; i < 10; ++i) out[b * 10 + i] = l[i] - lse;
    }
}

extern "C" void kernel_launch(void* const* d_in, const int* in_sizes, int n_in,
                              void* d_out, int out_size, void* d_ws, size_t ws_size,
                              hipStream_t stream) {
    const float* x     = (const float*)d_in[0];
    const float* f1    = (const float*)d_in[1];
    const float* f2    = (const float*)d_in[2];
    const float* f3    = (const float*)d_in[3];
    const float* f4    = (const float*)d_in[4];
    const float* f5    = (const float*)d_in[5];
    const float* gamma = (const float*)d_in[6];
    const float* beta  = (const float*)d_in[7];
    const float* W1    = (const float*)d_in[8];
    const float* b1    = (const float*)d_in[9];
    const float* W2    = (const float*)d_in[10];
    const float* b2    = (const float*)d_in[11];
    const float* W3    = (const float*)d_in[12];
    const float* b3    = (const float*)d_in[13];
    float* out = (float*)d_out;
    float* ws  = (float*)d_ws;

    float* PE = ws + WS_PE;
    float* PO = ws + WS_PO;
    float* C  = ws + WS_C;
    float* T  = ws + WS_T;
    float* K1  = ws + WS_K;
    float* K1T = K1 + 25312;
    float* K2  = K1 + 50624;
    float* K2T = K1 + 56839;
    float* K3  = K1 + 63054;
    float* K3T = K1 + 64539;
    float* K4  = K1 + 66024;
    float* K4T = K1 + 66375;
    float* AP = ws + WS_AP;
    float* H1 = ws + WS_H1;
    float* H2 = ws + WS_H2;
    float* P  = ws + WS_T;   // FC split-K partials (T is free by FC time)

    unsigned short* PK1 = (unsigned short*)(ws + WS_PK);
    unsigned short* PK2 = PK1 + 1024;
    unsigned short* PK3 = PK2 + 18432;
    unsigned short* PK4 = PK3 + 73728;
    unsigned short* PK5 = PK4 + 294912;

    // pooling matrices (exact DFT low-pass operators)
    gen_pool_mat<<<(113 * 224 + 255) / 256, 256, 0, stream>>>(K1, K1T, 113, 224);
    gen_pool_mat<<<(55 * 113 + 255) / 256, 256, 0, stream>>>(K2, K2T, 55, 113);
    gen_pool_mat<<<(27 * 55 + 255) / 256, 256, 0, stream>>>(K3, K3T, 27, 55);
    gen_pool_mat<<<(13 * 27 + 255) / 256, 256, 0, stream>>>(K4, K4T, 13, 27);

    // filter packs (A fragments, bf16)
    pack_f1_k<<<(2 * 512 + 255) / 256, 256, 0, stream>>>(f1, PK1);
    pack_f_k<<<(4 * 1 * 9 * 512 + 255) / 256, 256, 0, stream>>>(f2, PK2, 32, 64);
    pack_f_k<<<(8 * 2 * 9 * 512 + 255) / 256, 256, 0, stream>>>(f3, PK3, 64, 128);
    pack_f_k<<<(16 * 4 * 9 * 512 + 255) / 256, 256, 0, stream>>>(f4, PK4, 128, 256);
    pack_f_k<<<(16 * 8 * 9 * 512 + 255) / 256, 256, 0, stream>>>(f5, PK5, 256, 256);

    // ---- stage 1: conv1 (3->32, H=224) + pool to 113, chunks of 4 batches ----
    for (int ck = 0; ck < 4; ++ck) {
        int b0 = ck * 4;
        const float* xck = x + (size_t)b0 * 3 * 224 * 224;
        conv1_mfma_k<<<dim3(7, 1, 4 * 224), 256, 0, stream>>>(xck, PK1, C, 224);
        pool_row_k<<<dim3((113 + ST_R - 1) / ST_R, 4 * 32), 256, 0, stream>>>(C, K1, T, 113, 224);
        pool_col_k<<<dim3((113 + ST_C - 1) / ST_C, 4 * 32), 128, 0, stream>>>(
            T, K1T, PE + (size_t)b0 * 32 * 113 * 113, 113, 224, 1);
    }
    // ---- stage 2: conv2 (32->64, H=113) + pool to 55, chunks of 4 batches ----
    for (int ck = 0; ck < 4; ++ck) {
        int b0 = ck * 4;
        const float* pck = PE + (size_t)b0 * 32 * 113 * 113;
        conv_mfma_k<<<dim3(4, 2, 4 * 113), 256, 0, stream>>>(pck, PK2, C, 32, 64, 113);
        pool_row_k<<<dim3((55 + ST_R - 1) / ST_R, 4 * 64), 256, 0, stream>>>(C, K2, T, 55, 113);
        pool_col_k<<<dim3((55 + ST_C - 1) / ST_C, 4 * 64), 128, 0, stream>>>(
            T, K2T, PO + (size_t)b0 * 64 * 55 * 55, 55, 113, 1);
    }
    // ---- stage 3: conv3 (64->128, H=55) + pool to 27, full batch ----
    conv_mfma_k<<<dim3(2, 4, 16 * 55), 256, 0, stream>>>(PO, PK3, C, 64, 128, 55);
    pool_row_k<<<dim3((27 + ST_R - 1) / ST_R, 16 * 128), 256, 0, stream>>>(C, K3, T, 27, 55);
    pool_col_k<<<dim3((27 + ST_C - 1) / ST_C, 16 * 128), 128, 0, stream>>>(T, K3T, PE, 27, 55, 1);

    // ---- stage 4: conv4 (128->256, H=27) + pool to 13, full batch ----
    conv_mfma_k<<<dim3(1, 8, 16 * 27), 256, 0, stream>>>(PE, PK4, C, 128, 256, 27);
    pool_row_k<<<dim3((13 + ST_R - 1) / ST_R, 16 * 256), 256, 0, stream>>>(C, K4, T, 13, 27);
    pool_col_k<<<dim3((13 + ST_C - 1) / ST_C, 16 * 256), 128, 0, stream>>>(T, K4T, PO, 13, 27, 1);

    // ---- conv5 (256->256, H=13), no pool ----
    conv_mfma_k<<<dim3(1, 8, 16 * 13), 256, 0, stream>>>(PO, PK5, C, 256, 256, 13);

    // ---- batchnorm (in place) ----
    bn_k<<<256, 256, 0, stream>>>(C, gamma, beta);

    // ---- avg pool 3x3 stride 2 -> flattened (16, 9216) ----
    avgpool_k<<<(16 * 256 * 36 + 255) / 256, 256, 0, stream>>>(C, AP);

    // ---- FC head: split-K, then reduce+bias+relu ----
    fc_part_k<16, 256><<<dim3(512 / 64, 36), dim3(64, 4), 0, stream>>>(AP, W1, P, 9216, 512);
    fc_reduce_k<16><<<(16 * 512 + 255) / 256, 256, 0, stream>>>(P, b1, H1, 512, 36, 1);
    fc_part_k<16, 64><<<dim3(256 / 64, 8), dim3(64, 4), 0, stream>>>(H1, W2, P, 512, 256);
    fc_reduce_k<16><<<(16 * 256 + 255) / 256, 256, 0, stream>>>(P, b2, H2, 256, 8, 1);
    fc3_softmax_k<<<16, 64, 0, stream>>>(H2, W3, b3, out);
}

// Round 5
// 780.966 us; speedup vs baseline: 7.1912x; 1.4296x over previous
//
#include <hip/hip_runtime.h>
#include <hip/hip_bf16.h>

typedef __attribute__((ext_vector_type(8))) short short8_t;
typedef __attribute__((ext_vector_type(4))) float float4_t;

// ---------------- workspace layout (bytes) ----------------
#define OFF_CF  0u           // f32 conv-out scratch, max 4*32*224*224*4 = 25,690,112
#define OFF_PB1 25690112u    // bf16 pool1 out: 16*32*113*113*2 = 13,075,456
#define OFF_PB2 38765568u    // bf16 pool2 out: 16*64*55*55*2  =  6,195,200
#define OFF_PB3 44960768u    // bf16 pool3 out: 16*128*27*27*2 =  2,985,984
#define OFF_PB4 47946752u    // bf16 pool4 out: 16*256*13*13*2 =  1,384,448
#define OFF_C5  49331200u    // conv5 out f32: 16*256*169*4 = 2,768,896
#define OFF_AP  52100096u    // avgpool out f32: 16*9216*4 = 589,824
#define OFF_H1  52689920u    // fc1 out
#define OFF_H2  52722688u    // fc2 out
#define OFF_P   52739072u    // fc split-K partials: 36*16*512*4 = 1,179,648
#define OFF_FPK 53918720u    // filter packs: 977,920 ushort = 1,955,840 B
#define OFF_PPK 55874560u    // pool packs: 78,848 ushort = 157,696 B
// total ~56.1 MB

static __device__ __forceinline__ unsigned short f2bf(float v) {
    __hip_bfloat16 h = __float2bfloat16(v);
    return *(unsigned short*)&h;
}
static __device__ __forceinline__ float bf2f(unsigned short u) {
    __hip_bfloat16 h = *(__hip_bfloat16*)&u;
    return __bfloat162float(h);
}
static __device__ __forceinline__ unsigned short ld_bf(const float* p) { return f2bf(*p); }
static __device__ __forceinline__ unsigned short ld_bf(const unsigned short* p) { return *p; }
static __device__ __forceinline__ void st_out(float* p, float v) { *p = v; }
static __device__ __forceinline__ void st_out(unsigned short* p, float v) { *p = f2bf(v); }

// ---------------- filter pack: f(Ci,Co,3,3,2) -> A frags [Co/16][Ci/32][9][64][8] bf16 ----
__global__ void pack_f_k(const float* __restrict__ f, unsigned short* __restrict__ A,
                         int Ci, int Co) {
    int id = blockIdx.x * 256 + threadIdx.x;
    int nci = Ci >> 5;
    int total = (Co >> 4) * nci * 9 * 512;
    if (id >= total) return;
    int j = id & 7, lane = (id >> 3) & 63;
    int uv = (id >> 9) % 9;
    int rest = id / (512 * 9);
    int cc = rest % nci, co_blk = rest / nci;
    int m = lane & 15, k = ((lane >> 4) << 3) + j;
    int ci = (cc << 5) + k, co = (co_blk << 4) + m;
    A[id] = f2bf(f[((size_t)(ci * Co + co) * 9 + uv) * 2]);
}

// ---- conv1 pack: k = ci*9+uv (27, zero-padded to 32), layout [2][64][8] ----
__global__ void pack_f1_k(const float* __restrict__ f, unsigned short* __restrict__ A) {
    int id = blockIdx.x * 256 + threadIdx.x;
    if (id >= 2 * 512) return;
    int j = id & 7, lane = (id >> 3) & 63, co_blk = id >> 9;
    int m = lane & 15, k = ((lane >> 4) << 3) + j;
    float v = 0.f;
    if (k < 27) {
        int ci = k / 9, uv = k % 9;
        v = f[((size_t)(ci * 32 + co_blk * 16 + m) * 9 + uv) * 2];
    }
    A[id] = f2bf(v);
}

// ---------------- pool-matrix pack: K[row,col] frags, hi+lo bf16 ----------------
// layout: [rt][c][2][64][8]  (rt: 16-row tiles, c: 32-col chunks, hi/lo)
__global__ void pack_pool_k(unsigned short* __restrict__ P, int M, int N, int RT, int KC) {
    int id = blockIdx.x * 256 + threadIdx.x;
    if (id >= RT * KC * 512) return;
    int j = id & 7, lane = (id >> 3) & 63;
    int c = (id >> 9) % KC, rt = id / (512 * KC);
    int row = (rt << 4) + (lane & 15);
    int col = (c << 5) + ((lane >> 4) << 3) + j;
    double val = 0.0;
    if (row < M && col < N) {
        int n = (M - 1) / 2;
        double w = 6.283185307179586476925286766559 *
                   ((double)row / (double)M - (double)col / (double)N);
        double acc = 1.0;
        for (int a = 1; a <= n; ++a) acc += 2.0 * cos(w * (double)a);
        val = acc / (double)M;
    }
    float vf = (float)val;
    unsigned short hi = f2bf(vf);
    unsigned short lo = f2bf(vf - bf2f(hi));
    size_t base = ((size_t)(rt * KC + c) * 2) * 512 + lane * 8 + j;
    P[base] = hi;
    P[base + 512] = lo;
}

// ---------------- MFMA conv (Ci mult of 32, Co mult of 32): 9 shifted GEMMs ----------------
#define CPAD 40
template<typename Tin, typename Tout>
__global__ void conv_mfma_k(const Tin* __restrict__ x, const unsigned short* __restrict__ Apk,
                            Tout* __restrict__ y, int Ci, int Co, int H) {
    __shared__ unsigned short xs[3 * 34 * CPAD];
    int p = blockIdx.z % H, b = blockIdx.z / H;
    int q0 = blockIdx.x << 5;
    int co0 = blockIdx.y << 5;
    int tid = threadIdx.x;
    int lane = tid & 63, w = tid >> 6;
    int co_sub = w >> 1, n_sub = w & 1;
    int n_off = n_sub << 4;
    int nci = Ci >> 5;
    int kb = ((lane >> 4) << 3);
    float4_t acc = {0.f, 0.f, 0.f, 0.f};
    const Tin* xb = x + (size_t)b * Ci * H * H;
    int co_blk = (co0 >> 4) + co_sub;
    for (int cc = 0; cc < nci; ++cc) {
        for (int e = tid; e < 32 * 3 * 34; e += 256) {
            int ci = e / 102, rc = e % 102, r = rc / 34, c = rc % 34;
            int gp = p - 1 + r, gq = q0 - 1 + c;
            unsigned short v = 0;
            if ((unsigned)gp < (unsigned)H && (unsigned)gq < (unsigned)H)
                v = ld_bf(&xb[((size_t)((cc << 5) + ci) * H + gp) * H + gq]);
            xs[(r * 34 + c) * CPAD + ci] = v;
        }
        __syncthreads();
        const unsigned short* Ap = Apk + (((size_t)co_blk * nci + cc) * 9) * 512;
#pragma unroll
        for (int uv = 0; uv < 9; ++uv) {
            int u = uv / 3, v = uv % 3;
            short8_t af = *(const short8_t*)(Ap + ((uv * 64 + lane) << 3));
            int r = 2 - u;
            int c = n_off + (lane & 15) + 2 - v;
            short8_t bf = *(const short8_t*)(&xs[(r * 34 + c) * CPAD + kb]);
            acc = __builtin_amdgcn_mfma_f32_16x16x32_bf16(af, bf, acc, 0, 0, 0);
        }
        __syncthreads();
    }
    int n = lane & 15, mg = (lane >> 4) << 2;
    int q = q0 + n_off + n;
    if (q < H) {
        Tout* yb = y + (((size_t)b * Co + co0 + (co_sub << 4)) * H + p) * H + q;
#pragma unroll
        for (int r2 = 0; r2 < 4; ++r2)
            st_out(&yb[(size_t)(mg + r2) * H * H], acc[r2]);
    }
}

// ---------------- MFMA conv1 (Ci=3, Co=32): im2col K=27 padded to 32 ----------------
template<typename Tout>
__global__ void conv1_mfma_k(const float* __restrict__ x, const unsigned short* __restrict__ Apk,
                             Tout* __restrict__ y, int H) {
    __shared__ unsigned short xs[32 * CPAD];
    int p = blockIdx.z % H, b = blockIdx.z / H;
    int q0 = blockIdx.x << 5;
    int tid = threadIdx.x;
    int lane = tid & 63, w = tid >> 6;
    int co_sub = w >> 1, n_sub = w & 1;
    int n_off = n_sub << 4;
    int kb = ((lane >> 4) << 3);
    const float* xb = x + (size_t)b * 3 * H * H;
    for (int e = tid; e < 1024; e += 256) {
        int n = e >> 5, k = e & 31;
        float val = 0.f;
        if (k < 27) {
            int ci = k / 9, uv = k % 9, u = uv / 3, v = uv % 3;
            int gp = p + 1 - u, gq = q0 + n + 1 - v;
            if ((unsigned)gp < (unsigned)H && (unsigned)gq < (unsigned)H)
                val = xb[((size_t)ci * H + gp) * H + gq];
        }
        xs[n * CPAD + k] = f2bf(val);
    }
    __syncthreads();
    short8_t af = *(const short8_t*)(Apk + ((co_sub * 64 + lane) << 3));
    short8_t bf = *(const short8_t*)(&xs[(n_off + (lane & 15)) * CPAD + kb]);
    float4_t acc = {0.f, 0.f, 0.f, 0.f};
    acc = __builtin_amdgcn_mfma_f32_16x16x32_bf16(af, bf, acc, 0, 0, 0);
    int n = lane & 15, mg = (lane >> 4) << 2;
    int q = q0 + n_off + n;
    if (q < H) {
        Tout* yb = y + (((size_t)b * 32 + (co_sub << 4)) * H + p) * H + q;
#pragma unroll
        for (int r2 = 0; r2 < 4; ++r2)
            st_out(&yb[(size_t)(mg + r2) * H * H], acc[r2]);
    }
}

// ---------------- fused MFMA spectral pool, fp32-exact via hi+lo bf16 splits -----------
// in: f32 conv output. Pass 1: Z[u,t] = sum_v x[u,v] K[t,v]; x staged hi+lo, K hi+lo,
// 3-term products. Z stored TRANSPOSED in LDS as hi+lo planes. Pass 2:
// out[s,t] = sum_u K[s,u] Z[u,t], 3-term. Output relu -> bf16 (= next conv's input quant).
template<int N, int M, int TRT>
__global__ __launch_bounds__(256) void pool_mfma_k(const float* __restrict__ x,
                                                   const unsigned short* __restrict__ PK,
                                                   unsigned short* __restrict__ out) {
    constexpr int MT = (N + 15) / 16;     // u tiles (pass-1 m)
    constexpr int RT = (M + 15) / 16;     // s/t tiles
    constexpr int KC = (N + 31) / 32;     // k chunks
    constexpr int XPAD = 40;
    constexpr int ZPAD = KC * 32 + 8;     // covers full k-range; +8 shorts staggers banks
    constexpr int XROWS = MT * 16;
    constexpr int NT1 = MT * TRT;
    constexpr int L1 = (NT1 + 3) / 4;
    constexpr int NT2 = RT * TRT;
    constexpr int L2 = (NT2 + 3) / 4;
    __shared__ unsigned short xh[XROWS * XPAD], xl[XROWS * XPAD];
    __shared__ unsigned short zh[16 * TRT * ZPAD], zl[16 * TRT * ZPAD];

    int t0g = blockIdx.x * TRT;
    int bc = blockIdx.y;
    int tid = threadIdx.x;
    int lane = tid & 63, w = tid >> 6;
    int l15 = lane & 15;
    int kb = (lane >> 4) << 3;
    const float* xb = x + (size_t)bc * N * N;

    float4_t acc[L1];
#pragma unroll
    for (int i = 0; i < L1; ++i) acc[i] = (float4_t){0.f, 0.f, 0.f, 0.f};

    for (int c = 0; c < KC; ++c) {
        for (int id = tid; id < XROWS * 32; id += 256) {
            int u = id >> 5, vv = id & 31, v = (c << 5) + vv;
            float val = (u < N && v < N) ? xb[u * N + v] : 0.f;
            unsigned short hi = f2bf(val);
            xh[u * XPAD + vv] = hi;
            xl[u * XPAD + vv] = f2bf(val - bf2f(hi));
        }
        __syncthreads();
#pragma unroll
        for (int li = 0; li < L1; ++li) {
            int idx = li * 4 + w;
            if (idx < NT1) {
                int mt = idx / TRT, nt = idx % TRT;
                short8_t ahi = *(const short8_t*)(&xh[(mt * 16 + l15) * XPAD + kb]);
                short8_t alo = *(const short8_t*)(&xl[(mt * 16 + l15) * XPAD + kb]);
                const unsigned short* bp =
                    PK + ((size_t)((t0g + nt) * KC + c) * 2) * 512 + lane * 8;
                short8_t bhi = *(const short8_t*)bp;
                short8_t blo = *(const short8_t*)(bp + 512);
                acc[li] = __builtin_amdgcn_mfma_f32_16x16x32_bf16(ahi, bhi, acc[li], 0, 0, 0);
                acc[li] = __builtin_amdgcn_mfma_f32_16x16x32_bf16(ahi, blo, acc[li], 0, 0, 0);
                acc[li] = __builtin_amdgcn_mfma_f32_16x16x32_bf16(alo, bhi, acc[li], 0, 0, 0);
            }
        }
        __syncthreads();
    }
    // write Z^T hi+lo (bf16) to LDS; C-layout: col=lane&15 (=t), rows contiguous per lane
#pragma unroll
    for (int li = 0; li < L1; ++li) {
        int idx = li * 4 + w;
        if (idx < NT1) {
            int mt = idx / TRT, nt = idx % TRT;
            int t = nt * 16 + l15;
            int u0 = mt * 16 + ((lane >> 4) << 2);
            unsigned short h0 = f2bf(acc[li][0]), h1 = f2bf(acc[li][1]);
            unsigned short h2 = f2bf(acc[li][2]), h3 = f2bf(acc[li][3]);
            unsigned long long ph =
                (unsigned long long)h0 | ((unsigned long long)h1 << 16) |
                ((unsigned long long)h2 << 32) | ((unsigned long long)h3 << 48);
            unsigned long long pl =
                (unsigned long long)f2bf(acc[li][0] - bf2f(h0)) |
                ((unsigned long long)f2bf(acc[li][1] - bf2f(h1)) << 16) |
                ((unsigned long long)f2bf(acc[li][2] - bf2f(h2)) << 32) |
                ((unsigned long long)f2bf(acc[li][3] - bf2f(h3)) << 48);
            *(unsigned long long*)(&zh[t * ZPAD + u0]) = ph;
            *(unsigned long long*)(&zl[t * ZPAD + u0]) = pl;
        }
    }
    __syncthreads();

    float4_t acc2[L2];
#pragma unroll
    for (int i = 0; i < L2; ++i) acc2[i] = (float4_t){0.f, 0.f, 0.f, 0.f};
    for (int c = 0; c < KC; ++c) {
#pragma unroll
        for (int li = 0; li < L2; ++li) {
            int idx = li * 4 + w;
            if (idx < NT2) {
                int mt = idx / TRT, nt = idx % TRT;
                const unsigned short* ap =
                    PK + ((size_t)(mt * KC + c) * 2) * 512 + lane * 8;
                short8_t ahi = *(const short8_t*)ap;
                short8_t alo = *(const short8_t*)(ap + 512);
                short8_t bzh = *(const short8_t*)(&zh[(nt * 16 + l15) * ZPAD + (c << 5) + kb]);
                short8_t bzl = *(const short8_t*)(&zl[(nt * 16 + l15) * ZPAD + (c << 5) + kb]);
                acc2[li] = __builtin_amdgcn_mfma_f32_16x16x32_bf16(ahi, bzh, acc2[li], 0, 0, 0);
                acc2[li] = __builtin_amdgcn_mfma_f32_16x16x32_bf16(ahi, bzl, acc2[li], 0, 0, 0);
                acc2[li] = __builtin_amdgcn_mfma_f32_16x16x32_bf16(alo, bzh, acc2[li], 0, 0, 0);
            }
        }
    }
    unsigned short* ob = out + (size_t)bc * M * M;
#pragma unroll
    for (int li = 0; li < L2; ++li) {
        int idx = li * 4 + w;
        if (idx < NT2) {
            int mt = idx / TRT, nt = idx % TRT;
            int t = (t0g + nt) * 16 + l15;
            if (t < M) {
                int s0 = mt * 16 + ((lane >> 4) << 2);
#pragma unroll
                for (int r = 0; r < 4; ++r) {
                    int s = s0 + r;
                    if (s < M) ob[s * M + t] = f2bf(fmaxf(acc2[li][r], 0.f));
                }
            }
        }
    }
}

// ---------------- batchnorm over (B,H,W) per channel, in-place; h: (16,256,13,13) ----------------
__global__ void bn_k(float* __restrict__ h, const float* __restrict__ gamma,
                     const float* __restrict__ beta) {
    int c = blockIdx.x;
    int tid = threadIdx.x;
    float s = 0.f, s2 = 0.f;
    for (int i = tid; i < 16 * 169; i += 256) {
        int b = i / 169, hw = i % 169;
        float v = h[((size_t)b * 256 + c) * 169 + hw];
        s += v; s2 += v * v;
    }
    __shared__ float red[256], red2[256];
    red[tid] = s; red2[tid] = s2;
    __syncthreads();
    for (int st = 128; st > 0; st >>= 1) {
        if (tid < st) { red[tid] += red[tid + st]; red2[tid] += red2[tid + st]; }
        __syncthreads();
    }
    __shared__ float sc, sh;
    if (tid == 0) {
        float mean = red[0] / (16.f * 169.f);
        float var  = red2[0] / (16.f * 169.f) - mean * mean;
        float inv  = rsqrtf(var + 1e-5f);
        sc = gamma[c] * inv;
        sh = beta[c] - mean * sc;
    }
    __syncthreads();
    for (int i = tid; i < 16 * 169; i += 256) {
        int b = i / 169, hw = i % 169;
        size_t idx = ((size_t)b * 256 + c) * 169 + hw;
        h[idx] = h[idx] * sc + sh;
    }
}

// ---------------- 3x3 stride-2 VALID avg pool -> flattened (16, 9216) ----------------
__global__ void avgpool_k(const float* __restrict__ h, float* __restrict__ ap) {
    int id = blockIdx.x * 256 + threadIdx.x;
    if (id >= 16 * 256 * 36) return;
    int j = id % 6, i = (id / 6) % 6, c = (id / 36) % 256, b = id / (36 * 256);
    const float* hb = h + ((size_t)b * 256 + c) * 169;
    float s = 0.f;
#pragma unroll
    for (int di = 0; di < 3; ++di)
#pragma unroll
        for (int dj = 0; dj < 3; ++dj)
            s += hb[(2 * i + di) * 13 + (2 * j + dj)];
    ap[(size_t)b * 9216 + c * 36 + i * 6 + j] = s * (1.f / 9.f);
}

// ---------------- split-K FC partial kernel ----------------
template<int BATCH, int KLEN>
__global__ void fc_part_k(const float* __restrict__ h, const float* __restrict__ W,
                          float* __restrict__ P, int Kdim, int N) {
    __shared__ float hs[BATCH * KLEN];
    __shared__ float red[BATCH * 64];
    int tx = threadIdx.x, ty = threadIdx.y;
    int tid = ty * 64 + tx;
    int o = blockIdx.x * 64 + tx;
    int k0 = blockIdx.y * KLEN;
    for (int i = tid; i < BATCH * KLEN; i += 256) {
        int b = i / KLEN, k = i % KLEN;
        hs[i] = h[(size_t)b * Kdim + k0 + k];
    }
    __syncthreads();
    float acc[BATCH];
#pragma unroll
    for (int b = 0; b < BATCH; ++b) acc[b] = 0.f;
    for (int k = ty; k < KLEN; k += 4) {
        float w = W[(size_t)(k0 + k) * N + o];
#pragma unroll
        for (int b = 0; b < BATCH; ++b) acc[b] += hs[b * KLEN + k] * w;
    }
    for (int kz = 0; kz < 4; ++kz) {
        if (ty == kz) {
#pragma unroll
            for (int b = 0; b < BATCH; ++b) {
                if (kz == 0) red[b * 64 + tx] = acc[b];
                else         red[b * 64 + tx] += acc[b];
            }
        }
        __syncthreads();
    }
    if (ty == 0) {
#pragma unroll
        for (int b = 0; b < BATCH; ++b)
            P[((size_t)blockIdx.y * BATCH + b) * N + o] = red[b * 64 + tx];
    }
}

template<int BATCH>
__global__ void fc_reduce_k(const float* __restrict__ P, const float* __restrict__ bias,
                            float* __restrict__ out, int N, int KS, int relu) {
    int id = blockIdx.x * 256 + threadIdx.x;
    if (id >= BATCH * N) return;
    int b = id / N, o = id % N;
    float s = bias[o];
    for (int ks = 0; ks < KS; ++ks) s += P[((size_t)ks * BATCH + b) * N + o];
    if (relu) s = fmaxf(s, 0.f);
    out[(size_t)b * N + o] = s;
}

// ---------------- FC3 (256->10) + log_softmax ----------------
__global__ void fc3_softmax_k(const float* __restrict__ h, const float* __restrict__ W,
                              const float* __restrict__ bias, float* __restrict__ out) {
    int b = blockIdx.x;
    int o = threadIdx.x;
    __shared__ float l[10];
    if (o < 10) {
        float acc = bias[o];
        for (int k = 0; k < 256; ++k) acc += h[b * 256 + k] * W[k * 10 + o];
        l[o] = acc;
    }
    __syncthreads();
    if (o == 0) {
        float m = l[0];
        for (int i = 1; i < 10; ++i) m = fmaxf(m, l[i]);
        float s = 0.f;
        for (int i = 0; i < 10; ++i) s += expf(l[i] - m);
        float lse = m + logf(s);
        for (int i = 0; i < 10; ++i) out[b * 10 + i] = l[i] - lse;
    }
}

extern "C" void kernel_launch(void* const* d_in, const int* in_sizes, int n_in,
                              void* d_out, int out_size, void* d_ws, size_t ws_size,
                              hipStream_t stream) {
    const float* x     = (const float*)d_in[0];
    const float* f1    = (const float*)d_in[1];
    const float* f2    = (const float*)d_in[2];
    const float* f3    = (const float*)d_in[3];
    const float* f4    = (const float*)d_in[4];
    const float* f5    = (const float*)d_in[5];
    const float* gamma = (const float*)d_in[6];
    const float* beta  = (const float*)d_in[7];
    const float* W1    = (const float*)d_in[8];
    const float* b1    = (const float*)d_in[9];
    const float* W2    = (const float*)d_in[10];
    const float* b2    = (const float*)d_in[11];
    const float* W3    = (const float*)d_in[12];
    const float* b3    = (const float*)d_in[13];
    float* out = (float*)d_out;
    char* ws = (char*)d_ws;

    float* CF = (float*)(ws + OFF_CF);
    unsigned short* PB1 = (unsigned short*)(ws + OFF_PB1);
    unsigned short* PB2 = (unsigned short*)(ws + OFF_PB2);
    unsigned short* PB3 = (unsigned short*)(ws + OFF_PB3);
    unsigned short* PB4 = (unsigned short*)(ws + OFF_PB4);
    float* C5 = (float*)(ws + OFF_C5);
    float* AP = (float*)(ws + OFF_AP);
    float* H1 = (float*)(ws + OFF_H1);
    float* H2 = (float*)(ws + OFF_H2);
    float* P  = (float*)(ws + OFF_P);
    unsigned short* PK1 = (unsigned short*)(ws + OFF_FPK);
    unsigned short* PK2 = PK1 + 1024;
    unsigned short* PK3 = PK2 + 18432;
    unsigned short* PK4 = PK3 + 73728;
    unsigned short* PK5 = PK4 + 294912;
    unsigned short* PP1 = (unsigned short*)(ws + OFF_PPK);  // 8*7*1024 = 57344
    unsigned short* PP2 = PP1 + 57344;                      // 4*4*1024 = 16384
    unsigned short* PP3 = PP2 + 16384;                      // 2*2*1024 = 4096
    unsigned short* PP4 = PP3 + 4096;                       // 1*1*1024 = 1024

    // packs
    pack_f1_k<<<(2 * 512 + 255) / 256, 256, 0, stream>>>(f1, PK1);
    pack_f_k<<<(4 * 1 * 9 * 512 + 255) / 256, 256, 0, stream>>>(f2, PK2, 32, 64);
    pack_f_k<<<(8 * 2 * 9 * 512 + 255) / 256, 256, 0, stream>>>(f3, PK3, 64, 128);
    pack_f_k<<<(16 * 4 * 9 * 512 + 255) / 256, 256, 0, stream>>>(f4, PK4, 128, 256);
    pack_f_k<<<(16 * 8 * 9 * 512 + 255) / 256, 256, 0, stream>>>(f5, PK5, 256, 256);
    pack_pool_k<<<(8 * 7 * 512 + 255) / 256, 256, 0, stream>>>(PP1, 113, 224, 8, 7);
    pack_pool_k<<<(4 * 4 * 512 + 255) / 256, 256, 0, stream>>>(PP2, 55, 113, 4, 4);
    pack_pool_k<<<(2 * 2 * 512 + 255) / 256, 256, 0, stream>>>(PP3, 27, 55, 2, 2);
    pack_pool_k<<<(1 * 1 * 512 + 255) / 256, 256, 0, stream>>>(PP4, 13, 27, 1, 1);

    // ---- stage 1: conv1 (3->32, H=224) f32 out, pool 224->113 (bf16 out), 4-batch chunks
    for (int ck = 0; ck < 4; ++ck) {
        int b0 = ck * 4;
        conv1_mfma_k<float><<<dim3(7, 1, 4 * 224), 256, 0, stream>>>(
            x + (size_t)b0 * 3 * 224 * 224, PK1, CF, 224);
        pool_mfma_k<224, 113, 4><<<dim3(2, 4 * 32), 256, 0, stream>>>(
            CF, PP1, PB1 + (size_t)b0 * 32 * 113 * 113);
    }
    // ---- stage 2: conv2 (32->64, H=113) f32 out, pool 113->55, 4-batch chunks
    for (int ck = 0; ck < 4; ++ck) {
        int b0 = ck * 4;
        conv_mfma_k<unsigned short, float><<<dim3(4, 2, 4 * 113), 256, 0, stream>>>(
            PB1 + (size_t)b0 * 32 * 113 * 113, PK2, CF, 32, 64, 113);
        pool_mfma_k<113, 55, 4><<<dim3(1, 4 * 64), 256, 0, stream>>>(
            CF, PP2, PB2 + (size_t)b0 * 64 * 55 * 55);
    }
    // ---- stage 3: conv3 (64->128, H=55) full batch, pool 55->27
    conv_mfma_k<unsigned short, float><<<dim3(2, 4, 16 * 55), 256, 0, stream>>>(
        PB2, PK3, CF, 64, 128, 55);
    pool_mfma_k<55, 27, 2><<<dim3(1, 16 * 128), 256, 0, stream>>>(CF, PP3, PB3);
    // ---- stage 4: conv4 (128->256, H=27) full batch, pool 27->13
    conv_mfma_k<unsigned short, float><<<dim3(1, 8, 16 * 27), 256, 0, stream>>>(
        PB3, PK4, CF, 128, 256, 27);
    pool_mfma_k<27, 13, 1><<<dim3(1, 16 * 256), 256, 0, stream>>>(CF, PP4, PB4);
    // ---- conv5 (256->256, H=13) bf16 in, f32 out
    conv_mfma_k<unsigned short, float><<<dim3(1, 8, 16 * 13), 256, 0, stream>>>(
        PB4, PK5, C5, 256, 256, 13);

    // batchnorm + avgpool + FC head
    bn_k<<<256, 256, 0, stream>>>(C5, gamma, beta);
    avgpool_k<<<(16 * 256 * 36 + 255) / 256, 256, 0, stream>>>(C5, AP);
    fc_part_k<16, 256><<<dim3(512 / 64, 36), dim3(64, 4), 0, stream>>>(AP, W1, P, 9216, 512);
    fc_reduce_k<16><<<(16 * 512 + 255) / 256, 256, 0, stream>>>(P, b1, H1, 512, 36, 1);
    fc_part_k<16, 64><<<dim3(256 / 64, 8), dim3(64, 4), 0, stream>>>(H1, W2, P, 512, 256);
    fc_reduce_k<16><<<(16 * 256 + 255) / 256, 256, 0, stream>>>(P, b2, H2, 256, 8, 1);
    fc3_softmax_k<<<16, 64, 0, stream>>>(H2, W3, b3, out);
}

// Round 6
// 777.713 us; speedup vs baseline: 7.2213x; 1.0042x over previous
//
#include <hip/hip_runtime.h>
#include <hip/hip_bf16.h>

typedef __attribute__((ext_vector_type(8))) short short8_t;
typedef __attribute__((ext_vector_type(4))) float float4_t;

// ---------------- workspace layout (bytes) ----------------
#define OFF_CF  0u           // f32 conv-out scratch, max 4*32*224*224*4 = 25,690,112
#define OFF_PB1 25690112u    // bf16 pool1 out: 16*32*113*113*2 = 13,075,456
#define OFF_PB2 38765568u    // bf16 pool2 out: 16*64*55*55*2  =  6,195,200
#define OFF_PB3 44960768u    // bf16 pool3 out: 16*128*27*27*2 =  2,985,984
#define OFF_PB4 47946752u    // bf16 pool4 out: 16*256*13*13*2 =  1,384,448
#define OFF_C5  49331200u    // conv5 out f32: 16*256*169*4 = 2,768,896
#define OFF_AP  52100096u    // avgpool out f32: 16*9216*4 = 589,824
#define OFF_H1  52689920u    // fc1 out
#define OFF_H2  52722688u    // fc2 out
#define OFF_P   52739072u    // fc split-K partials: 36*16*512*4 = 1,179,648
#define OFF_FPK 53918720u    // filter packs: 986,112 ushort = 1,972,224 B
#define OFF_PPK 55890944u    // pool packs: 78,848 ushort = 157,696 B
// total ~56.05 MB

static __device__ __forceinline__ unsigned short f2bf(float v) {
    __hip_bfloat16 h = __float2bfloat16(v);
    return *(unsigned short*)&h;
}
static __device__ __forceinline__ float bf2f(unsigned short u) {
    __hip_bfloat16 h = *(__hip_bfloat16*)&u;
    return __bfloat162float(h);
}
static __device__ __forceinline__ unsigned short ld_bf(const float* p) { return f2bf(*p); }
static __device__ __forceinline__ unsigned short ld_bf(const unsigned short* p) { return *p; }
static __device__ __forceinline__ void st_out(float* p, float v) { *p = v; }
static __device__ __forceinline__ void st_out(unsigned short* p, float v) { *p = f2bf(v); }

// ---------------- filter pack: f(CIR,Co,3,3,2) -> A frags [cotile][cc][uv][64][8] bf16 ----
// ci beyond CIR (k-padding, e.g. conv1 Ci=3 padded to 32) packs as 0.
__global__ void pack_f_k(const float* __restrict__ f, unsigned short* __restrict__ A,
                         int Ci, int Co, int CIR) {
    int id = blockIdx.x * 256 + threadIdx.x;
    int nci = Ci >> 5;
    int total = (Co >> 4) * nci * 9 * 512;
    if (id >= total) return;
    int j = id & 7, lane = (id >> 3) & 63;
    int uv = (id >> 9) % 9;
    int rest = id / (512 * 9);
    int cc = rest % nci, co_blk = rest / nci;
    int m = lane & 15, k = ((lane >> 4) << 3) + j;
    int ci = (cc << 5) + k, co = (co_blk << 4) + m;
    float v = (ci < CIR) ? f[((size_t)(ci * Co + co) * 9 + uv) * 2] : 0.f;
    A[id] = f2bf(v);
}

// ---------------- pool-matrix pack: K[row,col] frags, hi+lo bf16 ----------------
__global__ void pack_pool_k(unsigned short* __restrict__ P, int M, int N, int RT, int KC) {
    int id = blockIdx.x * 256 + threadIdx.x;
    if (id >= RT * KC * 512) return;
    int j = id & 7, lane = (id >> 3) & 63;
    int c = (id >> 9) % KC, rt = id / (512 * KC);
    int row = (rt << 4) + (lane & 15);
    int col = (c << 5) + ((lane >> 4) << 3) + j;
    double val = 0.0;
    if (row < M && col < N) {
        int n = (M - 1) / 2;
        double w = 6.283185307179586476925286766559 *
                   ((double)row / (double)M - (double)col / (double)N);
        double acc = 1.0;
        for (int a = 1; a <= n; ++a) acc += 2.0 * cos(w * (double)a);
        val = acc / (double)M;
    }
    float vf = (float)val;
    unsigned short hi = f2bf(vf);
    unsigned short lo = f2bf(vf - bf2f(hi));
    size_t base = ((size_t)(rt * KC + c) * 2) * 512 + lane * 8 + j;
    P[base] = hi;
    P[base + 512] = lo;
}

// ---------------- MFMA conv v2: multi-p-row, multi-co slab, XOR-swizzled LDS ----------
// grid (ceil(H/(WQT*16)), ceil(H/PBLK), B * CO/COB). 9 shifted GEMMs over (u,v).
// LDS xs[rc][40 shorts]; ci-chunk (8 shorts = 16B) stored at slot (ci>>3)^((rc>>3)&3):
// bijective, keeps b128 reads 16B-aligned, spreads banks for both writes and reads.
template<int CI, int CIR, int CO, int COB, int PBLK, int WQT, typename Tin, typename Tout>
__global__ __launch_bounds__(256) void conv_mfma2_k(const Tin* __restrict__ x,
        const unsigned short* __restrict__ Apk, Tout* __restrict__ y, int H) {
    constexpr int ROWS = PBLK + 2;
    constexpr int QW = WQT * 16 + 2;
    constexpr int RC = ROWS * QW;
    constexpr int NCC = CI >> 5;
    constexpr int NCOG = CO / COB;
    constexpr int NC = (WQT == 2) ? (COB / 32) : (COB / 64);
    __shared__ unsigned short xs[RC * 40];
    int b = blockIdx.z / NCOG;
    int co0 = (blockIdx.z % NCOG) * COB;
    int q0 = blockIdx.x * (WQT * 16);
    int p0 = blockIdx.y * PBLK;
    int tid = threadIdx.x;
    int lane = tid & 63, w = tid >> 6;
    int l15 = lane & 15;
    int kch = lane >> 4;            // ci-chunk 0..3 (k-slot base kch*8)
    int mg = kch << 2;
    int qt = (WQT == 2) ? (w & 1) : 0;
    int ctb = (WQT == 2) ? ((w >> 1) * NC) : (w * NC);
    const Tin* xb = x + (size_t)b * CIR * H * H;
    float4_t acc[PBLK][NC];
#pragma unroll
    for (int pr = 0; pr < PBLK; ++pr)
#pragma unroll
        for (int nc = 0; nc < NC; ++nc) acc[pr][nc] = (float4_t){0.f, 0.f, 0.f, 0.f};
    for (int cc = 0; cc < NCC; ++cc) {
        for (int i = tid; i < RC * 32; i += 256) {
            int ci = i / RC;
            int rc = i - ci * RC;
            int r = rc / QW;
            int c = rc - r * QW;
            int gp = p0 - 1 + r, gq = q0 - 1 + c;
            unsigned short v = 0;
            if ((CI == CIR || ((cc << 5) + ci) < CIR) &&
                (unsigned)gp < (unsigned)H && (unsigned)gq < (unsigned)H)
                v = ld_bf(&xb[((size_t)((cc << 5) + ci) * H + gp) * H + gq]);
            xs[rc * 40 + ((((ci >> 3) ^ ((rc >> 3) & 3)) << 3) | (ci & 7))] = v;
        }
        __syncthreads();
#pragma unroll
        for (int uv = 0; uv < 9; ++uv) {
            const int u = uv / 3, v = uv % 3;
            short8_t af[NC];
#pragma unroll
            for (int nc = 0; nc < NC; ++nc) {
                int ct = (co0 >> 4) + ctb + nc;
                af[nc] = *(const short8_t*)(Apk +
                    (((size_t)ct * NCC + cc) * 9 + uv) * 512 + lane * 8);
            }
#pragma unroll
            for (int pr = 0; pr < PBLK; ++pr) {
                int rcL = (pr + 2 - u) * QW + qt * 16 + (2 - v) + l15;
                int addr = rcL * 40 + ((kch ^ ((rcL >> 3) & 3)) << 3);
                short8_t bf = *(const short8_t*)(&xs[addr]);
#pragma unroll
                for (int nc = 0; nc < NC; ++nc)
                    acc[pr][nc] = __builtin_amdgcn_mfma_f32_16x16x32_bf16(
                        af[nc], bf, acc[pr][nc], 0, 0, 0);
            }
        }
        __syncthreads();
    }
    int q = q0 + qt * 16 + l15;
    if (q < H) {
#pragma unroll
        for (int pr = 0; pr < PBLK; ++pr) {
            int p = p0 + pr;
            if (p < H) {
#pragma unroll
                for (int nc = 0; nc < NC; ++nc) {
                    Tout* yb = y + (((size_t)b * CO + co0 + (ctb + nc) * 16 + mg) * H + p) * H + q;
#pragma unroll
                    for (int r2 = 0; r2 < 4; ++r2)
                        st_out(&yb[(size_t)r2 * H * H], acc[pr][nc][r2]);
                }
            }
        }
    }
}

// ---------------- fused MFMA spectral pool, fp32-exact via hi+lo bf16 splits -----------
template<int N, int M, int TRT>
__global__ __launch_bounds__(256) void pool_mfma_k(const float* __restrict__ x,
                                                   const unsigned short* __restrict__ PK,
                                                   unsigned short* __restrict__ out) {
    constexpr int MT = (N + 15) / 16;
    constexpr int RT = (M + 15) / 16;
    constexpr int KC = (N + 31) / 32;
    constexpr int XPAD = 40;
    constexpr int ZPAD = KC * 32 + 8;
    constexpr int XROWS = MT * 16;
    constexpr int NT1 = MT * TRT;
    constexpr int L1 = (NT1 + 3) / 4;
    constexpr int NT2 = RT * TRT;
    constexpr int L2 = (NT2 + 3) / 4;
    __shared__ unsigned short xh[XROWS * XPAD], xl[XROWS * XPAD];
    __shared__ unsigned short zh[16 * TRT * ZPAD], zl[16 * TRT * ZPAD];

    int t0g = blockIdx.x * TRT;
    int bc = blockIdx.y;
    int tid = threadIdx.x;
    int lane = tid & 63, w = tid >> 6;
    int l15 = lane & 15;
    int kb = (lane >> 4) << 3;
    const float* xb = x + (size_t)bc * N * N;

    float4_t acc[L1];
#pragma unroll
    for (int i = 0; i < L1; ++i) acc[i] = (float4_t){0.f, 0.f, 0.f, 0.f};

    for (int c = 0; c < KC; ++c) {
        for (int id = tid; id < XROWS * 32; id += 256) {
            int u = id >> 5, vv = id & 31, v = (c << 5) + vv;
            float val = (u < N && v < N) ? xb[u * N + v] : 0.f;
            unsigned short hi = f2bf(val);
            xh[u * XPAD + vv] = hi;
            xl[u * XPAD + vv] = f2bf(val - bf2f(hi));
        }
        __syncthreads();
#pragma unroll
        for (int li = 0; li < L1; ++li) {
            int idx = li * 4 + w;
            if (idx < NT1) {
                int mt = idx / TRT, nt = idx % TRT;
                short8_t ahi = *(const short8_t*)(&xh[(mt * 16 + l15) * XPAD + kb]);
                short8_t alo = *(const short8_t*)(&xl[(mt * 16 + l15) * XPAD + kb]);
                const unsigned short* bp =
                    PK + ((size_t)((t0g + nt) * KC + c) * 2) * 512 + lane * 8;
                short8_t bhi = *(const short8_t*)bp;
                short8_t blo = *(const short8_t*)(bp + 512);
                acc[li] = __builtin_amdgcn_mfma_f32_16x16x32_bf16(ahi, bhi, acc[li], 0, 0, 0);
                acc[li] = __builtin_amdgcn_mfma_f32_16x16x32_bf16(ahi, blo, acc[li], 0, 0, 0);
                acc[li] = __builtin_amdgcn_mfma_f32_16x16x32_bf16(alo, bhi, acc[li], 0, 0, 0);
            }
        }
        __syncthreads();
    }
#pragma unroll
    for (int li = 0; li < L1; ++li) {
        int idx = li * 4 + w;
        if (idx < NT1) {
            int mt = idx / TRT, nt = idx % TRT;
            int t = nt * 16 + l15;
            int u0 = mt * 16 + ((lane >> 4) << 2);
            unsigned short h0 = f2bf(acc[li][0]), h1 = f2bf(acc[li][1]);
            unsigned short h2 = f2bf(acc[li][2]), h3 = f2bf(acc[li][3]);
            unsigned long long ph =
                (unsigned long long)h0 | ((unsigned long long)h1 << 16) |
                ((unsigned long long)h2 << 32) | ((unsigned long long)h3 << 48);
            unsigned long long pl =
                (unsigned long long)f2bf(acc[li][0] - bf2f(h0)) |
                ((unsigned long long)f2bf(acc[li][1] - bf2f(h1)) << 16) |
                ((unsigned long long)f2bf(acc[li][2] - bf2f(h2)) << 32) |
                ((unsigned long long)f2bf(acc[li][3] - bf2f(h3)) << 48);
            *(unsigned long long*)(&zh[t * ZPAD + u0]) = ph;
            *(unsigned long long*)(&zl[t * ZPAD + u0]) = pl;
        }
    }
    __syncthreads();

    float4_t acc2[L2];
#pragma unroll
    for (int i = 0; i < L2; ++i) acc2[i] = (float4_t){0.f, 0.f, 0.f, 0.f};
    for (int c = 0; c < KC; ++c) {
#pragma unroll
        for (int li = 0; li < L2; ++li) {
            int idx = li * 4 + w;
            if (idx < NT2) {
                int mt = idx / TRT, nt = idx % TRT;
                const unsigned short* ap =
                    PK + ((size_t)(mt * KC + c) * 2) * 512 + lane * 8;
                short8_t ahi = *(const short8_t*)ap;
                short8_t alo = *(const short8_t*)(ap + 512);
                short8_t bzh = *(const short8_t*)(&zh[(nt * 16 + l15) * ZPAD + (c << 5) + kb]);
                short8_t bzl = *(const short8_t*)(&zl[(nt * 16 + l15) * ZPAD + (c << 5) + kb]);
                acc2[li] = __builtin_amdgcn_mfma_f32_16x16x32_bf16(ahi, bzh, acc2[li], 0, 0, 0);
                acc2[li] = __builtin_amdgcn_mfma_f32_16x16x32_bf16(ahi, bzl, acc2[li], 0, 0, 0);
                acc2[li] = __builtin_amdgcn_mfma_f32_16x16x32_bf16(alo, bzh, acc2[li], 0, 0, 0);
            }
        }
    }
    unsigned short* ob = out + (size_t)bc * M * M;
#pragma unroll
    for (int li = 0; li < L2; ++li) {
        int idx = li * 4 + w;
        if (idx < NT2) {
            int mt = idx / TRT, nt = idx % TRT;
            int t = (t0g + nt) * 16 + l15;
            if (t < M) {
                int s0 = mt * 16 + ((lane >> 4) << 2);
#pragma unroll
                for (int r = 0; r < 4; ++r) {
                    int s = s0 + r;
                    if (s < M) ob[s * M + t] = f2bf(fmaxf(acc2[li][r], 0.f));
                }
            }
        }
    }
}

// ---------------- batchnorm over (B,H,W) per channel, in-place; h: (16,256,13,13) ----------------
__global__ void bn_k(float* __restrict__ h, const float* __restrict__ gamma,
                     const float* __restrict__ beta) {
    int c = blockIdx.x;
    int tid = threadIdx.x;
    float s = 0.f, s2 = 0.f;
    for (int i = tid; i < 16 * 169; i += 256) {
        int b = i / 169, hw = i % 169;
        float v = h[((size_t)b * 256 + c) * 169 + hw];
        s += v; s2 += v * v;
    }
    __shared__ float red[256], red2[256];
    red[tid] = s; red2[tid] = s2;
    __syncthreads();
    for (int st = 128; st > 0; st >>= 1) {
        if (tid < st) { red[tid] += red[tid + st]; red2[tid] += red2[tid + st]; }
        __syncthreads();
    }
    __shared__ float sc, sh;
    if (tid == 0) {
        float mean = red[0] / (16.f * 169.f);
        float var  = red2[0] / (16.f * 169.f) - mean * mean;
        float inv  = rsqrtf(var + 1e-5f);
        sc = gamma[c] * inv;
        sh = beta[c] - mean * sc;
    }
    __syncthreads();
    for (int i = tid; i < 16 * 169; i += 256) {
        int b = i / 169, hw = i % 169;
        size_t idx = ((size_t)b * 256 + c) * 169 + hw;
        h[idx] = h[idx] * sc + sh;
    }
}

// ---------------- 3x3 stride-2 VALID avg pool -> flattened (16, 9216) ----------------
__global__ void avgpool_k(const float* __restrict__ h, float* __restrict__ ap) {
    int id = blockIdx.x * 256 + threadIdx.x;
    if (id >= 16 * 256 * 36) return;
    int j = id % 6, i = (id / 6) % 6, c = (id / 36) % 256, b = id / (36 * 256);
    const float* hb = h + ((size_t)b * 256 + c) * 169;
    float s = 0.f;
#pragma unroll
    for (int di = 0; di < 3; ++di)
#pragma unroll
        for (int dj = 0; dj < 3; ++dj)
            s += hb[(2 * i + di) * 13 + (2 * j + dj)];
    ap[(size_t)b * 9216 + c * 36 + i * 6 + j] = s * (1.f / 9.f);
}

// ---------------- split-K FC partial kernel ----------------
template<int BATCH, int KLEN>
__global__ void fc_part_k(const float* __restrict__ h, const float* __restrict__ W,
                          float* __restrict__ P, int Kdim, int N) {
    __shared__ float hs[BATCH * KLEN];
    __shared__ float red[BATCH * 64];
    int tx = threadIdx.x, ty = threadIdx.y;
    int tid = ty * 64 + tx;
    int o = blockIdx.x * 64 + tx;
    int k0 = blockIdx.y * KLEN;
    for (int i = tid; i < BATCH * KLEN; i += 256) {
        int b = i / KLEN, k = i % KLEN;
        hs[i] = h[(size_t)b * Kdim + k0 + k];
    }
    __syncthreads();
    float acc[BATCH];
#pragma unroll
    for (int b = 0; b < BATCH; ++b) acc[b] = 0.f;
    for (int k = ty; k < KLEN; k += 4) {
        float w = W[(size_t)(k0 + k) * N + o];
#pragma unroll
        for (int b = 0; b < BATCH; ++b) acc[b] += hs[b * KLEN + k] * w;
    }
    for (int kz = 0; kz < 4; ++kz) {
        if (ty == kz) {
#pragma unroll
            for (int b = 0; b < BATCH; ++b) {
                if (kz == 0) red[b * 64 + tx] = acc[b];
                else         red[b * 64 + tx] += acc[b];
            }
        }
        __syncthreads();
    }
    if (ty == 0) {
#pragma unroll
        for (int b = 0; b < BATCH; ++b)
            P[((size_t)blockIdx.y * BATCH + b) * N + o] = red[b * 64 + tx];
    }
}

template<int BATCH>
__global__ void fc_reduce_k(const float* __restrict__ P, const float* __restrict__ bias,
                            float* __restrict__ out, int N, int KS, int relu) {
    int id = blockIdx.x * 256 + threadIdx.x;
    if (id >= BATCH * N) return;
    int b = id / N, o = id % N;
    float s = bias[o];
    for (int ks = 0; ks < KS; ++ks) s += P[((size_t)ks * BATCH + b) * N + o];
    if (relu) s = fmaxf(s, 0.f);
    out[(size_t)b * N + o] = s;
}

// ---------------- FC3 (256->10) + log_softmax ----------------
__global__ void fc3_softmax_k(const float* __restrict__ h, const float* __restrict__ W,
                              const float* __restrict__ bias, float* __restrict__ out) {
    int b = blockIdx.x;
    int o = threadIdx.x;
    __shared__ float l[10];
    if (o < 10) {
        float acc = bias[o];
        for (int k = 0; k < 256; ++k) acc += h[b * 256 + k] * W[k * 10 + o];
        l[o] = acc;
    }
    __syncthreads();
    if (o == 0) {
        float m = l[0];
        for (int i = 1; i < 10; ++i) m = fmaxf(m, l[i]);
        float s = 0.f;
        for (int i = 0; i < 10; ++i) s += expf(l[i] - m);
        float lse = m + logf(s);
        for (int i = 0; i < 10; ++i) out[b * 10 + i] = l[i] - lse;
    }
}

extern "C" void kernel_launch(void* const* d_in, const int* in_sizes, int n_in,
                              void* d_out, int out_size, void* d_ws, size_t ws_size,
                              hipStream_t stream) {
    const float* x     = (const float*)d_in[0];
    const float* f1    = (const float*)d_in[1];
    const float* f2    = (const float*)d_in[2];
    const float* f3    = (const float*)d_in[3];
    const float* f4    = (const float*)d_in[4];
    const float* f5    = (const float*)d_in[5];
    const float* gamma = (const float*)d_in[6];
    const float* beta  = (const float*)d_in[7];
    const float* W1    = (const float*)d_in[8];
    const float* b1    = (const float*)d_in[9];
    const float* W2    = (const float*)d_in[10];
    const float* b2    = (const float*)d_in[11];
    const float* W3    = (const float*)d_in[12];
    const float* b3    = (const float*)d_in[13];
    float* out = (float*)d_out;
    char* ws = (char*)d_ws;

    float* CF = (float*)(ws + OFF_CF);
    unsigned short* PB1 = (unsigned short*)(ws + OFF_PB1);
    unsigned short* PB2 = (unsigned short*)(ws + OFF_PB2);
    unsigned short* PB3 = (unsigned short*)(ws + OFF_PB3);
    unsigned short* PB4 = (unsigned short*)(ws + OFF_PB4);
    float* C5 = (float*)(ws + OFF_C5);
    float* AP = (float*)(ws + OFF_AP);
    float* H1 = (float*)(ws + OFF_H1);
    float* H2 = (float*)(ws + OFF_H2);
    float* P  = (float*)(ws + OFF_P);
    unsigned short* PK1 = (unsigned short*)(ws + OFF_FPK);   // 2*1*9*512  = 9216
    unsigned short* PK2 = PK1 + 9216;                        // 4*1*9*512  = 18432
    unsigned short* PK3 = PK2 + 18432;                       // 8*2*9*512  = 73728
    unsigned short* PK4 = PK3 + 73728;                       // 16*4*9*512 = 294912
    unsigned short* PK5 = PK4 + 294912;                      // 16*8*9*512 = 589824
    unsigned short* PP1 = (unsigned short*)(ws + OFF_PPK);   // 8*7*1024 = 57344
    unsigned short* PP2 = PP1 + 57344;                       // 4*4*1024 = 16384
    unsigned short* PP3 = PP2 + 16384;                       // 2*2*1024 = 4096
    unsigned short* PP4 = PP3 + 4096;                        // 1*1*1024 = 1024

    // packs
    pack_f_k<<<36,   256, 0, stream>>>(f1, PK1, 32, 32, 3);
    pack_f_k<<<72,   256, 0, stream>>>(f2, PK2, 32, 64, 32);
    pack_f_k<<<288,  256, 0, stream>>>(f3, PK3, 64, 128, 64);
    pack_f_k<<<1152, 256, 0, stream>>>(f4, PK4, 128, 256, 128);
    pack_f_k<<<2304, 256, 0, stream>>>(f5, PK5, 256, 256, 256);
    pack_pool_k<<<(8 * 7 * 512 + 255) / 256, 256, 0, stream>>>(PP1, 113, 224, 8, 7);
    pack_pool_k<<<(4 * 4 * 512 + 255) / 256, 256, 0, stream>>>(PP2, 55, 113, 4, 4);
    pack_pool_k<<<(2 * 2 * 512 + 255) / 256, 256, 0, stream>>>(PP3, 27, 55, 2, 2);
    pack_pool_k<<<(1 * 1 * 512 + 255) / 256, 256, 0, stream>>>(PP4, 13, 27, 1, 1);

    // ---- stage 1: conv1 (3->32 via k-pad, H=224) f32 out, pool 224->113, 4-batch chunks
    for (int ck = 0; ck < 4; ++ck) {
        int b0 = ck * 4;
        conv_mfma2_k<32, 3, 32, 32, 6, 2, float, float>
            <<<dim3(7, 38, 4), 256, 0, stream>>>(x + (size_t)b0 * 3 * 224 * 224, PK1, CF, 224);
        pool_mfma_k<224, 113, 4><<<dim3(2, 4 * 32), 256, 0, stream>>>(
            CF, PP1, PB1 + (size_t)b0 * 32 * 113 * 113);
    }
    // ---- stage 2: conv2 (32->64, H=113) f32 out, pool 113->55, 4-batch chunks
    for (int ck = 0; ck < 4; ++ck) {
        int b0 = ck * 4;
        conv_mfma2_k<32, 32, 64, 64, 6, 2, unsigned short, float>
            <<<dim3(4, 19, 4), 256, 0, stream>>>(PB1 + (size_t)b0 * 32 * 113 * 113, PK2, CF, 113);
        pool_mfma_k<113, 55, 4><<<dim3(1, 4 * 64), 256, 0, stream>>>(
            CF, PP2, PB2 + (size_t)b0 * 64 * 55 * 55);
    }
    // ---- stage 3: conv3 (64->128, H=55) full batch, pool 55->27
    conv_mfma2_k<64, 64, 128, 128, 6, 2, unsigned short, float>
        <<<dim3(2, 10, 16), 256, 0, stream>>>(PB2, PK3, CF, 55);
    pool_mfma_k<55, 27, 2><<<dim3(1, 16 * 128), 256, 0, stream>>>(CF, PP3, PB3);
    // ---- stage 4: conv4 (128->256, H=27) full batch, pool 27->13
    conv_mfma2_k<128, 128, 256, 128, 4, 2, unsigned short, float>
        <<<dim3(1, 7, 32), 256, 0, stream>>>(PB3, PK4, CF, 27);
    pool_mfma_k<27, 13, 1><<<dim3(1, 16 * 256), 256, 0, stream>>>(CF, PP4, PB4);
    // ---- conv5 (256->256, H=13) bf16 in, f32 out
    conv_mfma2_k<256, 256, 256, 128, 2, 1, unsigned short, float>
        <<<dim3(1, 7, 32), 256, 0, stream>>>(PB4, PK5, C5, 13);

    // batchnorm + avgpool + FC head
    bn_k<<<256, 256, 0, stream>>>(C5, gamma, beta);
    avgpool_k<<<(16 * 256 * 36 + 255) / 256, 256, 0, stream>>>(C5, AP);
    fc_part_k<16, 256><<<dim3(512 / 64, 36), dim3(64, 4), 0, stream>>>(AP, W1, P, 9216, 512);
    fc_reduce_k<16><<<(16 * 512 + 255) / 256, 256, 0, stream>>>(P, b1, H1, 512, 36, 1);
    fc_part_k<16, 64><<<dim3(256 / 64, 8), dim3(64, 4), 0, stream>>>(H1, W2, P, 512, 256);
    fc_reduce_k<16><<<(16 * 256 + 255) / 256, 256, 0, stream>>>(P, b2, H2, 256, 8, 1);
    fc3_softmax_k<<<16, 64, 0, stream>>>(H2, W3, b3, out);
}

// Round 8
// 631.330 us; speedup vs baseline: 8.8956x; 1.2319x over previous
//
#include <hip/hip_runtime.h>
#include <hip/hip_bf16.h>

typedef __attribute__((ext_vector_type(8))) short short8_t;
typedef __attribute__((ext_vector_type(4))) float float4_t;

// ---------------- workspace layout (bytes) ----------------
#define OFF_CF  0u           // f32 conv-out scratch, max 8*64*113*113*4 = 26,147,072
#define OFF_PB1 26214400u    // bf16 pool1 out (stride 120): 16*32*113*120*2 = 13,885,440
#define OFF_PB2 40099840u    // bf16 pool2 out (stride 56):  16*64*55*56*2  =  6,307,840
#define OFF_PB3 46407680u    // bf16 pool3 out (stride 32):  16*128*27*32*2 =  3,538,944
#define OFF_PB4 49946624u    // bf16 pool4 out (stride 16):  16*256*13*16*2 =  1,703,936
#define OFF_C5  51650560u    // conv5 out f32: 16*256*169*4 = 2,768,896
#define OFF_AP  54419456u    // avgpool out f32: 16*9216*4 = 589,824
#define OFF_H1  55009280u    // fc1 out
#define OFF_H2  55042048u    // fc2 out
#define OFF_P   55058432u    // fc split-K partials: 36*16*512*4 = 1,179,648
#define OFF_FPK 56238080u    // filter packs: 986,112 ushort = 1,972,224 B
#define OFF_PPK 58210304u    // pool packs: 78,848 ushort = 157,696 B
// total ~58.4 MB

static __device__ __forceinline__ unsigned short f2bf(float v) {
    __hip_bfloat16 h = __float2bfloat16(v);
    return *(unsigned short*)&h;
}
static __device__ __forceinline__ float bf2f(unsigned short u) {
    __hip_bfloat16 h = *(__hip_bfloat16*)&u;
    return __bfloat162float(h);
}
static __device__ __forceinline__ unsigned short ld_bf(const float* p) { return f2bf(*p); }
static __device__ __forceinline__ unsigned short ld_bf(const unsigned short* p) { return *p; }

// ---------------- unified filter pack: 5 layers in one kernel ----------------
__global__ void pack_f_all(const float* f1, const float* f2, const float* f3,
                           const float* f4, const float* f5,
                           unsigned short* A1, unsigned short* A2, unsigned short* A3,
                           unsigned short* A4, unsigned short* A5) {
    int bx = blockIdx.x;
    const float* f; unsigned short* A; int Ci, Co, CIR, base;
    if (bx < 36)        { f = f1; A = A1; Ci = 32;  Co = 32;  CIR = 3;   base = 0; }
    else if (bx < 108)  { f = f2; A = A2; Ci = 32;  Co = 64;  CIR = 32;  base = 36; }
    else if (bx < 396)  { f = f3; A = A3; Ci = 64;  Co = 128; CIR = 64;  base = 108; }
    else if (bx < 1548) { f = f4; A = A4; Ci = 128; Co = 256; CIR = 128; base = 396; }
    else                { f = f5; A = A5; Ci = 256; Co = 256; CIR = 256; base = 1548; }
    int id = (bx - base) * 256 + threadIdx.x;
    int nci = Ci >> 5;
    if (id >= (Co >> 4) * nci * 9 * 512) return;
    int j = id & 7, lane = (id >> 3) & 63;
    int uv = (id >> 9) % 9;
    int rest = id / (512 * 9);
    int cc = rest % nci, co_blk = rest / nci;
    int m = lane & 15, k = ((lane >> 4) << 3) + j;
    int ci = (cc << 5) + k, co = (co_blk << 4) + m;
    float v = (ci < CIR) ? f[((size_t)(ci * Co + co) * 9 + uv) * 2] : 0.f;
    A[id] = f2bf(v);
}

// ---------------- unified pool-matrix pack: 4 operators, hi+lo bf16 -----------
__global__ void pack_pool_all(unsigned short* P1, unsigned short* P2,
                              unsigned short* P3, unsigned short* P4) {
    int bx = blockIdx.x;
    unsigned short* P; int M, N, KC, base;
    if (bx < 112)      { P = P1; M = 113; N = 224; KC = 7; base = 0; }
    else if (bx < 144) { P = P2; M = 55;  N = 113; KC = 4; base = 112; }
    else if (bx < 152) { P = P3; M = 27;  N = 55;  KC = 2; base = 144; }
    else               { P = P4; M = 13;  N = 27;  KC = 1; base = 152; }
    int id = (bx - base) * 256 + threadIdx.x;
    int RT = (M + 15) / 16;
    if (id >= RT * KC * 512) return;
    int j = id & 7, lane = (id >> 3) & 63;
    int c = (id >> 9) % KC, rt = id / (512 * KC);
    int row = (rt << 4) + (lane & 15);
    int col = (c << 5) + ((lane >> 4) << 3) + j;
    double val = 0.0;
    if (row < M && col < N) {
        int n = (M - 1) / 2;
        double w = 6.283185307179586476925286766559 *
                   ((double)row / (double)M - (double)col / (double)N);
        double acc = 1.0;
        for (int a = 1; a <= n; ++a) acc += 2.0 * cos(w * (double)a);
        val = acc / (double)M;
    }
    float vf = (float)val;
    unsigned short hi = f2bf(vf);
    unsigned short lo = f2bf(vf - bf2f(hi));
    size_t bo = ((size_t)(rt * KC + c) * 2) * 512 + lane * 8 + j;
    P[bo] = hi;
    P[bo + 512] = lo;
}

// ---------------- MFMA conv v3: vectorized staging, XOR-swizzled LDS ----------
// grid (ceil(H/(WQT*16)), ceil(H/PBLK), B * CO/COB). Input rows strided HS (mult of 8).
template<int CI, int CIR, int CO, int COB, int PBLK, int WQT, typename Tin>
__global__ __launch_bounds__(256) void conv_mfma3_k(const Tin* __restrict__ x,
        const unsigned short* __restrict__ Apk, float* __restrict__ y, int H, int HS) {
    constexpr int ROWS = PBLK + 2;
    constexpr int QW = WQT * 16 + 2;
    constexpr int QCH8 = (QW + 14) / 8;
    constexpr int RC = ROWS * QW;
    constexpr int NCC = CI >> 5;
    constexpr int NCOG = CO / COB;
    constexpr int NC = (WQT == 2) ? (COB / 32) : (COB / 64);
    __shared__ unsigned short xs[RC * 40];
    int b = blockIdx.z / NCOG;
    int co0 = (blockIdx.z % NCOG) * COB;
    int q0 = blockIdx.x * (WQT * 16);
    int p0 = blockIdx.y * PBLK;
    int tid = threadIdx.x;
    int lane = tid & 63, w = tid >> 6;
    int l15 = lane & 15;
    int kch = lane >> 4;
    int mg = kch << 2;
    int qt = (WQT == 2) ? (w & 1) : 0;
    int ctb = (WQT == 2) ? ((w >> 1) * NC) : (w * NC);
    const Tin* xb = x + (size_t)b * CIR * H * HS;
    float4_t acc[PBLK][NC];
#pragma unroll
    for (int pr = 0; pr < PBLK; ++pr)
#pragma unroll
        for (int nc = 0; nc < NC; ++nc) acc[pr][nc] = (float4_t){0.f, 0.f, 0.f, 0.f};
    for (int cc = 0; cc < NCC; ++cc) {
        for (int i = tid; i < 32 * ROWS * QCH8; i += 256) {
            int ci = i / (ROWS * QCH8);
            int rem = i - ci * (ROWS * QCH8);
            int r = rem / QCH8, ch = rem - r * QCH8;
            int gci = (cc << 5) + ci;
            int gp = p0 - 1 + r;
            int gq0 = q0 - 8 + ch * 8;
            bool rowok = (CI == CIR || gci < CIR) && ((unsigned)gp < (unsigned)H);
            unsigned short vv[8];
            if (rowok && ch >= 1 && ch * 8 <= QW - 1 && gq0 >= 0 && gq0 + 7 < H) {
                const Tin* src = &xb[((size_t)gci * H + gp) * HS + gq0];
                if constexpr (sizeof(Tin) == 2) {
                    short8_t v8 = *(const short8_t*)src;
#pragma unroll
                    for (int j = 0; j < 8; ++j) vv[j] = (unsigned short)v8[j];
                } else {
                    float4_t f0 = *(const float4_t*)src;
                    float4_t g0 = *(const float4_t*)(src + 4);
#pragma unroll
                    for (int j = 0; j < 4; ++j) { vv[j] = f2bf(f0[j]); vv[4 + j] = f2bf(g0[j]); }
                }
            } else {
#pragma unroll
                for (int j = 0; j < 8; ++j) {
                    int gq = gq0 + j;
                    unsigned short u = 0;
                    if (rowok && (unsigned)gq < (unsigned)H)
                        u = ld_bf(&xb[((size_t)gci * H + gp) * HS + gq]);
                    vv[j] = u;
                }
            }
#pragma unroll
            for (int j = 0; j < 8; ++j) {
                int c8 = ch * 8 + j - 7;
                if ((unsigned)c8 < (unsigned)QW) {
                    int rc = r * QW + c8;
                    xs[rc * 40 + ((((ci >> 3) ^ ((rc >> 3) & 3)) << 3) | (ci & 7))] = vv[j];
                }
            }
        }
        __syncthreads();
#pragma unroll
        for (int uv = 0; uv < 9; ++uv) {
            const int u = uv / 3, v = uv % 3;
            short8_t af[NC];
#pragma unroll
            for (int nc = 0; nc < NC; ++nc) {
                int ct = (co0 >> 4) + ctb + nc;
                af[nc] = *(const short8_t*)(Apk +
                    (((size_t)ct * NCC + cc) * 9 + uv) * 512 + lane * 8);
            }
#pragma unroll
            for (int pr = 0; pr < PBLK; ++pr) {
                int rcL = (pr + 2 - u) * QW + qt * 16 + (2 - v) + l15;
                int addr = rcL * 40 + ((kch ^ ((rcL >> 3) & 3)) << 3);
                short8_t bf = *(const short8_t*)(&xs[addr]);
#pragma unroll
                for (int nc = 0; nc < NC; ++nc)
                    acc[pr][nc] = __builtin_amdgcn_mfma_f32_16x16x32_bf16(
                        af[nc], bf, acc[pr][nc], 0, 0, 0);
            }
        }
        __syncthreads();
    }
    int q = q0 + qt * 16 + l15;
    if (q < H) {
#pragma unroll
        for (int pr = 0; pr < PBLK; ++pr) {
            int p = p0 + pr;
            if (p < H) {
#pragma unroll
                for (int nc = 0; nc < NC; ++nc) {
                    float* yb = y + (((size_t)b * CO + co0 + (ctb + nc) * 16 + mg) * H + p) * H + q;
#pragma unroll
                    for (int r2 = 0; r2 < 4; ++r2)
                        yb[(size_t)r2 * H * H] = acc[pr][nc][r2];
                }
            }
        }
    }
}

// ---------------- fused MFMA spectral pool, fp32-exact via hi+lo bf16 splits ---------
template<int N, int M, int TRT, int MS>
__global__ __launch_bounds__(256) void pool_mfma_k(const float* __restrict__ x,
                                                   const unsigned short* __restrict__ PK,
                                                   unsigned short* __restrict__ out) {
    constexpr int MT = (N + 15) / 16;
    constexpr int RT = (M + 15) / 16;
    constexpr int KC = (N + 31) / 32;
    constexpr int XPAD = 40;
    constexpr int ZPAD = KC * 32 + 8;
    constexpr int XROWS = MT * 16;
    constexpr int NT1 = MT * TRT;
    constexpr int L1 = (NT1 + 3) / 4;
    constexpr int NT2 = RT * TRT;
    constexpr int L2 = (NT2 + 3) / 4;
    __shared__ unsigned short xh[XROWS * XPAD], xl[XROWS * XPAD];
    __shared__ unsigned short zh[16 * TRT * ZPAD], zl[16 * TRT * ZPAD];

    int t0g = blockIdx.x * TRT;
    int bc = blockIdx.y;
    int tid = threadIdx.x;
    int lane = tid & 63, w = tid >> 6;
    int l15 = lane & 15;
    int kb = (lane >> 4) << 3;
    const float* xb = x + (size_t)bc * N * N;

    float4_t acc[L1];
#pragma unroll
    for (int i = 0; i < L1; ++i) acc[i] = (float4_t){0.f, 0.f, 0.f, 0.f};

    for (int c = 0; c < KC; ++c) {
        for (int id = tid; id < XROWS * 32; id += 256) {
            int u = id >> 5, vv = id & 31, v = (c << 5) + vv;
            float val = (u < N && v < N) ? xb[u * N + v] : 0.f;
            unsigned short hi = f2bf(val);
            xh[u * XPAD + vv] = hi;
            xl[u * XPAD + vv] = f2bf(val - bf2f(hi));
        }
        __syncthreads();
#pragma unroll
        for (int li = 0; li < L1; ++li) {
            int idx = li * 4 + w;
            if (idx < NT1) {
                int mt = idx / TRT, nt = idx % TRT;
                short8_t ahi = *(const short8_t*)(&xh[(mt * 16 + l15) * XPAD + kb]);
                short8_t alo = *(const short8_t*)(&xl[(mt * 16 + l15) * XPAD + kb]);
                const unsigned short* bp =
                    PK + ((size_t)((t0g + nt) * KC + c) * 2) * 512 + lane * 8;
                short8_t bhi = *(const short8_t*)bp;
                short8_t blo = *(const short8_t*)(bp + 512);
                acc[li] = __builtin_amdgcn_mfma_f32_16x16x32_bf16(ahi, bhi, acc[li], 0, 0, 0);
                acc[li] = __builtin_amdgcn_mfma_f32_16x16x32_bf16(ahi, blo, acc[li], 0, 0, 0);
                acc[li] = __builtin_amdgcn_mfma_f32_16x16x32_bf16(alo, bhi, acc[li], 0, 0, 0);
            }
        }
        __syncthreads();
    }
#pragma unroll
    for (int li = 0; li < L1; ++li) {
        int idx = li * 4 + w;
        if (idx < NT1) {
            int mt = idx / TRT, nt = idx % TRT;
            int t = nt * 16 + l15;
            int u0 = mt * 16 + ((lane >> 4) << 2);
            unsigned short h0 = f2bf(acc[li][0]), h1 = f2bf(acc[li][1]);
            unsigned short h2 = f2bf(acc[li][2]), h3 = f2bf(acc[li][3]);
            unsigned long long ph =
                (unsigned long long)h0 | ((unsigned long long)h1 << 16) |
                ((unsigned long long)h2 << 32) | ((unsigned long long)h3 << 48);
            unsigned long long pl =
                (unsigned long long)f2bf(acc[li][0] - bf2f(h0)) |
                ((unsigned long long)f2bf(acc[li][1] - bf2f(h1)) << 16) |
                ((unsigned long long)f2bf(acc[li][2] - bf2f(h2)) << 32) |
                ((unsigned long long)f2bf(acc[li][3] - bf2f(h3)) << 48);
            *(unsigned long long*)(&zh[t * ZPAD + u0]) = ph;
            *(unsigned long long*)(&zl[t * ZPAD + u0]) = pl;
        }
    }
    __syncthreads();

    float4_t acc2[L2];
#pragma unroll
    for (int i = 0; i < L2; ++i) acc2[i] = (float4_t){0.f, 0.f, 0.f, 0.f};
    for (int c = 0; c < KC; ++c) {
#pragma unroll
        for (int li = 0; li < L2; ++li) {
            int idx = li * 4 + w;
            if (idx < NT2) {
                int mt = idx / TRT, nt = idx % TRT;
                const unsigned short* ap =
                    PK + ((size_t)(mt * KC + c) * 2) * 512 + lane * 8;
                short8_t ahi = *(const short8_t*)ap;
                short8_t alo = *(const short8_t*)(ap + 512);
                short8_t bzh = *(const short8_t*)(&zh[(nt * 16 + l15) * ZPAD + (c << 5) + kb]);
                short8_t bzl = *(const short8_t*)(&zl[(nt * 16 + l15) * ZPAD + (c << 5) + kb]);
                acc2[li] = __builtin_amdgcn_mfma_f32_16x16x32_bf16(ahi, bzh, acc2[li], 0, 0, 0);
                acc2[li] = __builtin_amdgcn_mfma_f32_16x16x32_bf16(ahi, bzl, acc2[li], 0, 0, 0);
                acc2[li] = __builtin_amdgcn_mfma_f32_16x16x32_bf16(alo, bzh, acc2[li], 0, 0, 0);
            }
        }
    }
    unsigned short* ob = out + (size_t)bc * M * MS;
#pragma unroll
    for (int li = 0; li < L2; ++li) {
        int idx = li * 4 + w;
        if (idx < NT2) {
            int mt = idx / TRT, nt = idx % TRT;
            int t = (t0g + nt) * 16 + l15;
            if (t < M) {
                int s0 = mt * 16 + ((lane >> 4) << 2);
#pragma unroll
                for (int r = 0; r < 4; ++r) {
                    int s = s0 + r;
                    if (s < M) ob[s * MS + t] = f2bf(fmaxf(acc2[li][r], 0.f));
                }
            }
        }
    }
}

// ---------------- fused batchnorm + 3x3/s2 avgpool -> flattened (16,9216) -----------
__global__ __launch_bounds__(256) void bn_avgpool_k(const float* __restrict__ h,
        const float* __restrict__ gamma, const float* __restrict__ beta,
        float* __restrict__ ap) {
    int c = blockIdx.x, tid = threadIdx.x;
    __shared__ float hs[16 * 169];
    __shared__ float red[256], red2[256];
    float s = 0.f, s2 = 0.f;
    for (int i = tid; i < 16 * 169; i += 256) {
        int b = i / 169, hw = i % 169;
        float v = h[((size_t)b * 256 + c) * 169 + hw];
        hs[i] = v; s += v; s2 += v * v;
    }
    red[tid] = s; red2[tid] = s2;
    __syncthreads();
    for (int st = 128; st > 0; st >>= 1) {
        if (tid < st) { red[tid] += red[tid + st]; red2[tid] += red2[tid + st]; }
        __syncthreads();
    }
    __shared__ float sc, sh;
    if (tid == 0) {
        float mean = red[0] / (16.f * 169.f);
        float var  = red2[0] / (16.f * 169.f) - mean * mean;
        float inv  = rsqrtf(var + 1e-5f);
        sc = gamma[c] * inv;
        sh = beta[c] - mean * sc;
    }
    __syncthreads();
    for (int i = tid; i < 16 * 36; i += 256) {
        int b = i / 36, r = i % 36, ii = r / 6, jj = r % 6;
        const float* hb = &hs[b * 169];
        float sum = 0.f;
#pragma unroll
        for (int di = 0; di < 3; ++di)
#pragma unroll
            for (int dj = 0; dj < 3; ++dj)
                sum += hb[(2 * ii + di) * 13 + 2 * jj + dj];
        ap[(size_t)b * 9216 + c * 36 + r] = sum * (1.f / 9.f) * sc + sh;
    }
}

// ---------------- split-K FC partial kernel ----------------
template<int BATCH, int KLEN>
__global__ void fc_part_k(const float* __restrict__ h, const float* __restrict__ W,
                          float* __restrict__ P, int Kdim, int N) {
    __shared__ float hs[BATCH * KLEN];
    __shared__ float red[BATCH * 64];
    int tx = threadIdx.x, ty = threadIdx.y;
    int tid = ty * 64 + tx;
    int o = blockIdx.x * 64 + tx;
    int k0 = blockIdx.y * KLEN;
    for (int i = tid; i < BATCH * KLEN; i += 256) {
        int b = i / KLEN, k = i % KLEN;
        hs[i] = h[(size_t)b * Kdim + k0 + k];
    }
    __syncthreads();
    float acc[BATCH];
#pragma unroll
    for (int b = 0; b < BATCH; ++b) acc[b] = 0.f;
    for (int k = ty; k < KLEN; k += 4) {
        float w = W[(size_t)(k0 + k) * N + o];
#pragma unroll
        for (int b = 0; b < BATCH; ++b) acc[b] += hs[b * KLEN + k] * w;
    }
    for (int kz = 0; kz < 4; ++kz) {
        if (ty == kz) {
#pragma unroll
            for (int b = 0; b < BATCH; ++b) {
                if (kz == 0) red[b * 64 + tx] = acc[b];
                else         red[b * 64 + tx] += acc[b];
            }
        }
        __syncthreads();
    }
    if (ty == 0) {
#pragma unroll
        for (int b = 0; b < BATCH; ++b)
            P[((size_t)blockIdx.y * BATCH + b) * N + o] = red[b * 64 + tx];
    }
}

template<int BATCH>
__global__ void fc_reduce_k(const float* __restrict__ P, const float* __restrict__ bias,
                            float* __restrict__ out, int N, int KS, int relu) {
    int id = blockIdx.x * 256 + threadIdx.x;
    if (id >= BATCH * N) return;
    int b = id / N, o = id % N;
    float s = bias[o];
    for (int ks = 0; ks < KS; ++ks) s += P[((size_t)ks * BATCH + b) * N + o];
    if (relu) s = fmaxf(s, 0.f);
    out[(size_t)b * N + o] = s;
}

// ---------------- FC3 (256->10) + log_softmax ----------------
__global__ void fc3_softmax_k(const float* __restrict__ h, const float* __restrict__ W,
                              const float* __restrict__ bias, float* __restrict__ out) {
    int b = blockIdx.x;
    int o = threadIdx.x;
    __shared__ float l[10];
    if (o < 10) {
        float acc = bias[o];
        for (int k = 0; k < 256; ++k) acc += h[b * 256 + k] * W[k * 10 + o];
        l[o] = acc;
    }
    __syncthreads();
    if (o == 0) {
        float m = l[0];
        for (int i = 1; i < 10; ++i) m = fmaxf(m, l[i]);
        float s = 0.f;
        for (int i = 0; i < 10; ++i) s += expf(l[i] - m);
        float lse = m + logf(s);
        for (int i = 0; i < 10; ++i) out[b * 10 + i] = l[i] - lse;
    }
}

extern "C" void kernel_launch(void* const* d_in, const int* in_sizes, int n_in,
                              void* d_out, int out_size, void* d_ws, size_t ws_size,
                              hipStream_t stream) {
    const float* x     = (const float*)d_in[0];
    const float* f1    = (const float*)d_in[1];
    const float* f2    = (const float*)d_in[2];
    const float* f3    = (const float*)d_in[3];
    const float* f4    = (const float*)d_in[4];
    const float* f5    = (const float*)d_in[5];
    const float* gamma = (const float*)d_in[6];
    const float* beta  = (const float*)d_in[7];
    const float* W1    = (const float*)d_in[8];
    const float* b1    = (const float*)d_in[9];
    const float* W2    = (const float*)d_in[10];
    const float* b2    = (const float*)d_in[11];
    const float* W3    = (const float*)d_in[12];
    const float* b3    = (const float*)d_in[13];
    float* out = (float*)d_out;
    char* ws = (char*)d_ws;

    float* CF = (float*)(ws + OFF_CF);
    unsigned short* PB1 = (unsigned short*)(ws + OFF_PB1);
    unsigned short* PB2 = (unsigned short*)(ws + OFF_PB2);
    unsigned short* PB3 = (unsigned short*)(ws + OFF_PB3);
    unsigned short* PB4 = (unsigned short*)(ws + OFF_PB4);
    float* C5 = (float*)(ws + OFF_C5);
    float* AP = (float*)(ws + OFF_AP);
    float* H1 = (float*)(ws + OFF_H1);
    float* H2 = (float*)(ws + OFF_H2);
    float* P  = (float*)(ws + OFF_P);
    unsigned short* PK1 = (unsigned short*)(ws + OFF_FPK);   // 9216
    unsigned short* PK2 = PK1 + 9216;                        // 18432
    unsigned short* PK3 = PK2 + 18432;                       // 73728
    unsigned short* PK4 = PK3 + 73728;                       // 294912
    unsigned short* PK5 = PK4 + 294912;                      // 589824
    unsigned short* PP1 = (unsigned short*)(ws + OFF_PPK);   // 57344
    unsigned short* PP2 = PP1 + 57344;                       // 16384
    unsigned short* PP3 = PP2 + 16384;                       // 4096
    unsigned short* PP4 = PP3 + 4096;                        // 1024

    // packs (2 launches)
    pack_f_all<<<3852, 256, 0, stream>>>(f1, f2, f3, f4, f5, PK1, PK2, PK3, PK4, PK5);
    pack_pool_all<<<154, 256, 0, stream>>>(PP1, PP2, PP3, PP4);

    // ---- stage 1: 4-batch chunks (conv1 f32 out = 25.69 MB fits CF; 8-batch would
    //      overflow into PB1 — that was R7's failure) ----
    for (int ck = 0; ck < 4; ++ck) {
        int b0 = ck * 4;
        conv_mfma3_k<32, 3, 32, 32, 6, 2, float>
            <<<dim3(7, 38, 4), 256, 0, stream>>>(x + (size_t)b0 * 3 * 224 * 224, PK1, CF, 224, 224);
        pool_mfma_k<224, 113, 4, 120><<<dim3(2, 4 * 32), 256, 0, stream>>>(
            CF, PP1, PB1 + (size_t)b0 * 32 * 113 * 120);
    }
    // ---- stage 2: 8-batch chunks (CF = 26.15 MB fits) ----
    for (int ck = 0; ck < 2; ++ck) {
        int b0 = ck * 8;
        conv_mfma3_k<32, 32, 64, 64, 6, 2, unsigned short>
            <<<dim3(4, 19, 8), 256, 0, stream>>>(PB1 + (size_t)b0 * 32 * 113 * 120, PK2, CF, 113, 120);
        pool_mfma_k<113, 55, 4, 56><<<dim3(1, 8 * 64), 256, 0, stream>>>(
            CF, PP2, PB2 + (size_t)b0 * 64 * 55 * 56);
    }
    // ---- stage 3: conv3 (64->128, H=55), pool 55->27 ----
    conv_mfma3_k<64, 64, 128, 64, 6, 2, unsigned short>
        <<<dim3(2, 10, 32), 256, 0, stream>>>(PB2, PK3, CF, 55, 56);
    pool_mfma_k<55, 27, 2, 32><<<dim3(1, 16 * 128), 256, 0, stream>>>(CF, PP3, PB3);
    // ---- stage 4: conv4 (128->256, H=27), pool 27->13 ----
    conv_mfma3_k<128, 128, 256, 64, 4, 2, unsigned short>
        <<<dim3(1, 7, 64), 256, 0, stream>>>(PB3, PK4, CF, 27, 32);
    pool_mfma_k<27, 13, 1, 16><<<dim3(1, 16 * 256), 256, 0, stream>>>(CF, PP4, PB4);
    // ---- conv5 (256->256, H=13) ----
    conv_mfma3_k<256, 256, 256, 64, 2, 1, unsigned short>
        <<<dim3(1, 7, 64), 256, 0, stream>>>(PB4, PK5, C5, 13, 16);

    // fused bn+avgpool, FC head
    bn_avgpool_k<<<256, 256, 0, stream>>>(C5, gamma, beta, AP);
    fc_part_k<16, 256><<<dim3(512 / 64, 36), dim3(64, 4), 0, stream>>>(AP, W1, P, 9216, 512);
    fc_reduce_k<16><<<(16 * 512 + 255) / 256, 256, 0, stream>>>(P, b1, H1, 512, 36, 1);
    fc_part_k<16, 64><<<dim3(256 / 64, 8), dim3(64, 4), 0, stream>>>(H1, W2, P, 512, 256);
    fc_reduce_k<16><<<(16 * 256 + 255) / 256, 256, 0, stream>>>(P, b2, H2, 256, 8, 1);
    fc3_softmax_k<<<16, 64, 0, stream>>>(H2, W3, b3, out);
}